// Round 3
// baseline (2614.727 us; speedup 1.0000x reference)
//
#include <hip/hip_runtime.h>
#include <math.h>

#define TOKS 8192
#define HDIM 768
#define FDIM 3072
#define NEXP 8
#define NHEAD 12
#define SEQ 1024
#define BATCH 8

// ============ generic tiled f32 GEMM: C[M,N] = A[M,K]@B[K,N] + bias ============
// grid: (N/64, M/64), block 256. M,N mult of 64; K mult of 16.
__global__ __launch_bounds__(256) void gemm_bias_kernel(
    const float* __restrict__ A, const float* __restrict__ Bw,
    const float* __restrict__ bias, float* __restrict__ C,
    int M, int N, int K)
{
  __shared__ float As[16][68];   // [k][m], pad->2-way conflicts only
  __shared__ float Bs[16][68];   // [k][n]
  const int tid = threadIdx.x;
  const int tx = tid & 15, ty = tid >> 4;
  const int row0 = blockIdx.y * 64;
  const int col0 = blockIdx.x * 64;
  const int alr = tid >> 2, alc = (tid & 3) << 2;   // A: 64 rows x 16 k
  const int blr = tid >> 4, blc = (tid & 15) << 2;  // B: 16 k x 64 n
  float acc[4][4] = {};
  for (int k0 = 0; k0 < K; k0 += 16) {
    const float4 a4 = *reinterpret_cast<const float4*>(&A[(size_t)(row0 + alr) * K + (k0 + alc)]);
    const float4 b4 = *reinterpret_cast<const float4*>(&Bw[(size_t)(k0 + blr) * N + (col0 + blc)]);
    __syncthreads();
    As[alc + 0][alr] = a4.x;
    As[alc + 1][alr] = a4.y;
    As[alc + 2][alr] = a4.z;
    As[alc + 3][alr] = a4.w;
    *reinterpret_cast<float4*>(&Bs[blr][blc]) = b4;
    __syncthreads();
#pragma unroll
    for (int kk = 0; kk < 16; ++kk) {
      const float4 av = *reinterpret_cast<const float4*>(&As[kk][ty << 2]);
      const float4 bv = *reinterpret_cast<const float4*>(&Bs[kk][tx << 2]);
      const float am[4] = {av.x, av.y, av.z, av.w};
      const float bm[4] = {bv.x, bv.y, bv.z, bv.w};
#pragma unroll
      for (int i = 0; i < 4; ++i)
#pragma unroll
        for (int j = 0; j < 4; ++j)
          acc[i][j] = fmaf(am[i], bm[j], acc[i][j]);
    }
  }
#pragma unroll
  for (int i = 0; i < 4; ++i) {
    const int r = row0 + (ty << 2) + i;
#pragma unroll
    for (int j = 0; j < 4; ++j) {
      const int c = col0 + (tx << 2) + j;
      C[(size_t)r * N + c] = acc[i][j] + bias[c];
    }
  }
}

// ============ expert up-proj: inter[tok] = gelu(X[tok] @ Wi[e] + bi[e]) ============
// grid: (128, FDIM/64, NEXP), block 256. Rows gathered via perm within expert segment.
__global__ __launch_bounds__(256) void expert_up_kernel(
    const float* __restrict__ X, const float* __restrict__ Wi,
    const float* __restrict__ bi, const int* __restrict__ perm,
    const int* __restrict__ offs, float* __restrict__ inter)
{
  const int e = blockIdx.z;
  const int seg_start = offs[e], seg_end = offs[e + 1];
  const int row0 = seg_start + blockIdx.x * 64;
  if (row0 >= seg_end) return;
  __shared__ float As[16][68];
  __shared__ float Bs[16][68];
  __shared__ int toks[64];
  const int tid = threadIdx.x;
  const int tx = tid & 15, ty = tid >> 4;
  const int col0 = blockIdx.y * 64;
  const int alr = tid >> 2, alc = (tid & 3) << 2;
  const int blr = tid >> 4, blc = (tid & 15) << 2;
  if (tid < 64) {
    const int rr = row0 + tid;
    toks[tid] = (rr < seg_end) ? perm[rr] : -1;
  }
  __syncthreads();
  const int mytok = toks[alr];
  const float* Bw = Wi + (size_t)e * HDIM * FDIM;
  float acc[4][4] = {};
  for (int k0 = 0; k0 < HDIM; k0 += 16) {
    float4 a4 = make_float4(0.f, 0.f, 0.f, 0.f);
    if (mytok >= 0)
      a4 = *reinterpret_cast<const float4*>(&X[(size_t)mytok * HDIM + (k0 + alc)]);
    const float4 b4 = *reinterpret_cast<const float4*>(&Bw[(size_t)(k0 + blr) * FDIM + (col0 + blc)]);
    __syncthreads();
    As[alc + 0][alr] = a4.x;
    As[alc + 1][alr] = a4.y;
    As[alc + 2][alr] = a4.z;
    As[alc + 3][alr] = a4.w;
    *reinterpret_cast<float4*>(&Bs[blr][blc]) = b4;
    __syncthreads();
#pragma unroll
    for (int kk = 0; kk < 16; ++kk) {
      const float4 av = *reinterpret_cast<const float4*>(&As[kk][ty << 2]);
      const float4 bv = *reinterpret_cast<const float4*>(&Bs[kk][tx << 2]);
      const float am[4] = {av.x, av.y, av.z, av.w};
      const float bm[4] = {bv.x, bv.y, bv.z, bv.w};
#pragma unroll
      for (int i = 0; i < 4; ++i)
#pragma unroll
        for (int j = 0; j < 4; ++j)
          acc[i][j] = fmaf(am[i], bm[j], acc[i][j]);
    }
  }
#pragma unroll
  for (int i = 0; i < 4; ++i) {
    const int tok = toks[(ty << 2) + i];
    if (tok < 0) continue;
#pragma unroll
    for (int j = 0; j < 4; ++j) {
      const int c = col0 + (tx << 2) + j;
      float v = acc[i][j] + bi[(size_t)e * FDIM + c];
      v = 0.5f * v * (1.0f + erff(v * 0.70710678118654752f));  // exact gelu
      inter[(size_t)tok * FDIM + c] = v;
    }
  }
}

// ============ flash attention: non-causal, DH=64 ============
// grid: (SEQ/64, NHEAD, BATCH), block 256. Q,K,V,ctx layout [B*S, H] with head offset h*64.
// Each 64x64 f32 tile is 1024 float4s -> each of 256 threads loads FOUR float4s.
__global__ __launch_bounds__(256) void attention_kernel(
    const float* __restrict__ Q, const float* __restrict__ K,
    const float* __restrict__ V, float* __restrict__ ctx)
{
  __shared__ float QtT[64][68];  // [d][qrow], pre-scaled by 1/8
  __shared__ float KtT[64][68];  // [d][krow]
  __shared__ float Vt[64][68];   // [krow][d]
  __shared__ float StT[64][68];  // [krow][qrow]
  __shared__ float mrow[64], lrow[64], crow[64];
  const int tid = threadIdx.x;
  const int tx = tid & 15, ty = tid >> 4;
  const int b = blockIdx.z, h = blockIdx.y;
  const int q0 = blockIdx.x * 64;
  const size_t base = (size_t)b * SEQ * HDIM + (size_t)h * 64;
  const int lr = tid >> 2, lc = (tid & 3) << 2;   // row 0..63, d-sub 0/4/8/12
#pragma unroll
  for (int d0 = 0; d0 < 64; d0 += 16) {
    const float4 q4 = *reinterpret_cast<const float4*>(
        &Q[base + (size_t)(q0 + lr) * HDIM + d0 + lc]);
    QtT[d0 + lc + 0][lr] = q4.x * 0.125f;
    QtT[d0 + lc + 1][lr] = q4.y * 0.125f;
    QtT[d0 + lc + 2][lr] = q4.z * 0.125f;
    QtT[d0 + lc + 3][lr] = q4.w * 0.125f;
  }
  if (tid < 64) { mrow[tid] = -3.0e38f; lrow[tid] = 0.f; }
  float o[4][4] = {};
  for (int kt = 0; kt < SEQ; kt += 64) {
    float4 k4[4], v4[4];
#pragma unroll
    for (int c = 0; c < 4; ++c) {
      k4[c] = *reinterpret_cast<const float4*>(
          &K[base + (size_t)(kt + lr) * HDIM + c * 16 + lc]);
      v4[c] = *reinterpret_cast<const float4*>(
          &V[base + (size_t)(kt + lr) * HDIM + c * 16 + lc]);
    }
    __syncthreads();   // previous tile fully consumed (also covers QtT/stats init)
#pragma unroll
    for (int c = 0; c < 4; ++c) {
      KtT[c * 16 + lc + 0][lr] = k4[c].x;
      KtT[c * 16 + lc + 1][lr] = k4[c].y;
      KtT[c * 16 + lc + 2][lr] = k4[c].z;
      KtT[c * 16 + lc + 3][lr] = k4[c].w;
      *reinterpret_cast<float4*>(&Vt[lr][c * 16 + lc]) = v4[c];
    }
    __syncthreads();
    // --- S = (Q/8) @ K^T, 4x4 per thread ---
    float s[4][4] = {};
#pragma unroll
    for (int d = 0; d < 64; ++d) {
      const float4 qv = *reinterpret_cast<const float4*>(&QtT[d][ty << 2]);
      const float4 kv = *reinterpret_cast<const float4*>(&KtT[d][tx << 2]);
      const float qa[4] = {qv.x, qv.y, qv.z, qv.w};
      const float kb[4] = {kv.x, kv.y, kv.z, kv.w};
#pragma unroll
      for (int i = 0; i < 4; ++i)
#pragma unroll
        for (int j = 0; j < 4; ++j)
          s[i][j] = fmaf(qa[i], kb[j], s[i][j]);
    }
#pragma unroll
    for (int i = 0; i < 4; ++i)
#pragma unroll
      for (int j = 0; j < 4; ++j)
        StT[(tx << 2) + j][(ty << 2) + i] = s[i][j];
    __syncthreads();
    // --- online softmax: 4 lanes per row ---
    {
      const int r = tid >> 2, sl = tid & 3;
      const float m_old = mrow[r];
      float mx = m_old;
#pragma unroll
      for (int k2 = sl * 16; k2 < sl * 16 + 16; ++k2) mx = fmaxf(mx, StT[k2][r]);
      mx = fmaxf(mx, __shfl_xor(mx, 1));
      mx = fmaxf(mx, __shfl_xor(mx, 2));
      float sum = 0.f;
#pragma unroll
      for (int k2 = sl * 16; k2 < sl * 16 + 16; ++k2) {
        const float p = expf(StT[k2][r] - mx);
        StT[k2][r] = p;
        sum += p;
      }
      sum += __shfl_xor(sum, 1);
      sum += __shfl_xor(sum, 2);
      if (sl == 0) {
        const float corr = expf(m_old - mx);
        crow[r] = corr;
        lrow[r] = lrow[r] * corr + sum;
        mrow[r] = mx;
      }
    }
    __syncthreads();
    // --- O = O*corr + P @ V ---
    float cf[4];
#pragma unroll
    for (int i = 0; i < 4; ++i) cf[i] = crow[(ty << 2) + i];
#pragma unroll
    for (int i = 0; i < 4; ++i)
#pragma unroll
      for (int j = 0; j < 4; ++j) o[i][j] *= cf[i];
#pragma unroll
    for (int k2 = 0; k2 < 64; ++k2) {
      const float4 pv = *reinterpret_cast<const float4*>(&StT[k2][ty << 2]);
      const float4 vv = *reinterpret_cast<const float4*>(&Vt[k2][tx << 2]);
      const float pa[4] = {pv.x, pv.y, pv.z, pv.w};
      const float vb[4] = {vv.x, vv.y, vv.z, vv.w};
#pragma unroll
      for (int i = 0; i < 4; ++i)
#pragma unroll
        for (int j = 0; j < 4; ++j)
          o[i][j] = fmaf(pa[i], vb[j], o[i][j]);
    }
  }
#pragma unroll
  for (int i = 0; i < 4; ++i) {
    const int r = (ty << 2) + i;
    const float inv = 1.f / lrow[r];
#pragma unroll
    for (int j = 0; j < 4; ++j)
      ctx[base + (size_t)(q0 + r) * HDIM + (tx << 2) + j] = o[i][j] * inv;
  }
}

// ============ residual add + LayerNorm: out = g*(x+r - mu)*rstd + b ============
// grid: TOKS, block 256 (3 elems/thread, H=768)
__global__ __launch_bounds__(256) void add_ln_kernel(
    const float* __restrict__ X, const float* __restrict__ R,
    const float* __restrict__ g, const float* __restrict__ bb,
    float* __restrict__ out)
{
  const int t = blockIdx.x;
  const int tid = threadIdx.x;
  const float* x = X + (size_t)t * HDIM;
  const float* r = R + (size_t)t * HDIM;
  float v[3];
  float sum = 0.f, ssq = 0.f;
#pragma unroll
  for (int i = 0; i < 3; ++i) {
    const float val = x[tid + i * 256] + r[tid + i * 256];
    v[i] = val;
    sum += val;
    ssq += val * val;
  }
#pragma unroll
  for (int o = 32; o > 0; o >>= 1) {
    sum += __shfl_down(sum, o);
    ssq += __shfl_down(ssq, o);
  }
  __shared__ float red[10];
  const int wid = tid >> 6, lane = tid & 63;
  if (lane == 0) { red[wid] = sum; red[4 + wid] = ssq; }
  __syncthreads();
  if (tid == 0) {
    const float s = red[0] + red[1] + red[2] + red[3];
    const float q = red[4] + red[5] + red[6] + red[7];
    const float mean = s * (1.f / HDIM);
    const float var = q * (1.f / HDIM) - mean * mean;
    red[8] = mean;
    red[9] = rsqrtf(fmaxf(var, 0.f) + 1e-12f);
  }
  __syncthreads();
  const float mean = red[8], rstd = red[9];
#pragma unroll
  for (int i = 0; i < 3; ++i) {
    const int idx = tid + i * 256;
    out[(size_t)t * HDIM + idx] = g[idx] * (v[i] - mean) * rstd + bb[idx];
  }
}

// ============ router: scores=softmax(X@Wr+br), expert=argmax, counts ============
// grid: TOKS/4, block 256 (one wave per token)
__global__ __launch_bounds__(256) void router_kernel(
    const float* __restrict__ X, const float* __restrict__ Wr,
    const float* __restrict__ br, float* __restrict__ scores_out,
    int* __restrict__ expert, int* __restrict__ counts)
{
  const int wid = threadIdx.x >> 6, lane = threadIdx.x & 63;
  const int tok = blockIdx.x * 4 + wid;
  const float* x = X + (size_t)tok * HDIM;
  float acc[8] = {};
  for (int k0 = 0; k0 < HDIM; k0 += 64) {
    const float xv = x[k0 + lane];
    const float* wrow = Wr + (size_t)(k0 + lane) * NEXP;
    const float4 w0 = *reinterpret_cast<const float4*>(wrow);
    const float4 w1 = *reinterpret_cast<const float4*>(wrow + 4);
    acc[0] = fmaf(xv, w0.x, acc[0]);
    acc[1] = fmaf(xv, w0.y, acc[1]);
    acc[2] = fmaf(xv, w0.z, acc[2]);
    acc[3] = fmaf(xv, w0.w, acc[3]);
    acc[4] = fmaf(xv, w1.x, acc[4]);
    acc[5] = fmaf(xv, w1.y, acc[5]);
    acc[6] = fmaf(xv, w1.z, acc[6]);
    acc[7] = fmaf(xv, w1.w, acc[7]);
  }
#pragma unroll
  for (int e = 0; e < 8; ++e)
#pragma unroll
    for (int o = 32; o > 0; o >>= 1) acc[e] += __shfl_down(acc[e], o);
  if (lane == 0) {
    float mx = -3.0e38f;
#pragma unroll
    for (int e = 0; e < 8; ++e) { acc[e] += br[e]; mx = fmaxf(mx, acc[e]); }
    float sum = 0.f;
#pragma unroll
    for (int e = 0; e < 8; ++e) { acc[e] = expf(acc[e] - mx); sum += acc[e]; }
    const float inv = 1.f / sum;
    int best = 0;
    float bv = acc[0];
#pragma unroll
    for (int e = 0; e < 8; ++e) {
      const float p = acc[e] * inv;
      scores_out[(size_t)tok * NEXP + e] = p;
      if (acc[e] > bv) { bv = acc[e]; best = e; }
    }
    expert[tok] = best;
    atomicAdd(&counts[best], 1);
  }
}

__global__ void offsets_kernel(const int* __restrict__ counts, int* __restrict__ offs)
{
  if (threadIdx.x == 0 && blockIdx.x == 0) {
    int a = 0;
    for (int e = 0; e < NEXP; ++e) { offs[e] = a; a += counts[e]; }
    offs[NEXP] = a;
  }
}

__global__ __launch_bounds__(256) void scatter_kernel(
    const int* __restrict__ expert, const int* __restrict__ offs,
    int* __restrict__ cursor, int* __restrict__ perm)
{
  const int t = blockIdx.x * 256 + threadIdx.x;
  if (t >= TOKS) return;
  const int e = expert[t];
  const int pos = atomicAdd(&cursor[e], 1);
  perm[offs[e] + pos] = t;
}

extern "C" void kernel_launch(void* const* d_in, const int* in_sizes, int n_in,
                              void* d_out, int out_size, void* d_ws, size_t ws_size,
                              hipStream_t stream) {
  const float* hidden = (const float*)d_in[0];
  const float* Wq  = (const float*)d_in[1];
  const float* bq  = (const float*)d_in[2];
  const float* Wk  = (const float*)d_in[3];
  const float* bk  = (const float*)d_in[4];
  const float* Wv  = (const float*)d_in[5];
  const float* bv  = (const float*)d_in[6];
  const float* Wao = (const float*)d_in[7];
  const float* bao = (const float*)d_in[8];
  const float* ln1g = (const float*)d_in[9];
  const float* ln1b = (const float*)d_in[10];
  const float* Wr  = (const float*)d_in[11];
  const float* br  = (const float*)d_in[12];
  const float* Wi  = (const float*)d_in[13];
  const float* bi  = (const float*)d_in[14];
  const float* Wo  = (const float*)d_in[15];
  const float* bo  = (const float*)d_in[16];
  const float* ln2g = (const float*)d_in[17];
  const float* ln2b = (const float*)d_in[18];

  float* out = (float*)d_out;
  float* scores_out = out + (size_t)TOKS * HDIM;

  const size_t M1 = (size_t)TOKS * HDIM;   // 6.29M floats
  const size_t M2 = (size_t)TOKS * FDIM;   // 25.2M floats
  float* ws = (float*)d_ws;
  // arena (aliased by liveness):
  float* Qb       = ws;            // [0, M1)
  float* Kb       = ws + M1;       // [M1, 2M1)
  float* Vb       = ws + 2 * M1;   // [2M1, 3M1)
  float* ctxb     = ws + 3 * M1;   // [3M1, 4M1)  (inside future inter region, dead by then)
  float* aoproj   = ws;            // reuse Q
  float* attn_out = ws + M1;       // reuse K
  float* inter    = ws + 2 * M1;   // [2M1, 2M1+M2)
  float* tmp2     = ws;            // reuse Q/aoproj
  int* ints   = (int*)(ws + 2 * M1 + M2);
  int* perm   = ints;
  int* expert = ints + TOKS;
  int* counts = expert + TOKS;
  int* offs   = counts + NEXP;
  int* cursor = offs + NEXP + 1;

  hipMemsetAsync(counts, 0, (NEXP + NEXP + 1 + NEXP) * sizeof(int), stream);

  const dim3 blk(256);
  const dim3 g_h(HDIM / 64, TOKS / 64);   // (12,128)
  gemm_bias_kernel<<<g_h, blk, 0, stream>>>(hidden, Wq, bq, Qb, TOKS, HDIM, HDIM);
  gemm_bias_kernel<<<g_h, blk, 0, stream>>>(hidden, Wk, bk, Kb, TOKS, HDIM, HDIM);
  gemm_bias_kernel<<<g_h, blk, 0, stream>>>(hidden, Wv, bv, Vb, TOKS, HDIM, HDIM);

  attention_kernel<<<dim3(SEQ / 64, NHEAD, BATCH), blk, 0, stream>>>(Qb, Kb, Vb, ctxb);

  gemm_bias_kernel<<<g_h, blk, 0, stream>>>(ctxb, Wao, bao, aoproj, TOKS, HDIM, HDIM);
  add_ln_kernel<<<dim3(TOKS), blk, 0, stream>>>(aoproj, hidden, ln1g, ln1b, attn_out);

  router_kernel<<<dim3(TOKS / 4), blk, 0, stream>>>(attn_out, Wr, br, scores_out, expert, counts);
  offsets_kernel<<<dim3(1), dim3(64), 0, stream>>>(counts, offs);
  scatter_kernel<<<dim3(TOKS / 256), blk, 0, stream>>>(expert, offs, cursor, perm);

  expert_up_kernel<<<dim3(TOKS / 64, FDIM / 64, NEXP), blk, 0, stream>>>(
      attn_out, Wi, bi, perm, offs, inter);

  gemm_bias_kernel<<<dim3(HDIM / 64, TOKS / 64), blk, 0, stream>>>(
      inter, Wo, bo, tmp2, TOKS, HDIM, FDIM);
  add_ln_kernel<<<dim3(TOKS), blk, 0, stream>>>(tmp2, attn_out, ln2g, ln2b, out);
}

// Round 4
// 1755.388 us; speedup vs baseline: 1.4895x; 1.4895x over previous
//
#include <hip/hip_runtime.h>
#include <math.h>
#include <stdint.h>

#define TOKS 8192
#define HDIM 768
#define FDIM 3072
#define NEXP 8
#define NHEAD 12
#define SEQ 1024
#define BATCH 8

typedef __attribute__((ext_vector_type(8))) short s16x8;   // 8 bf16 = 4 VGPR
typedef __attribute__((ext_vector_type(4))) short s16x4;
typedef __attribute__((ext_vector_type(4))) float f32x4;

__device__ __forceinline__ short f2bf(float f) {
  uint32_t u = __float_as_uint(f);
  uint32_t r = (u + 0x7fffu + ((u >> 16) & 1u)) >> 16;   // RTN-even
  return (short)(r & 0xffffu);
}

__device__ __forceinline__ void gload16(const void* g, void* l) {
  __builtin_amdgcn_global_load_lds(
      (const __attribute__((address_space(1))) uint32_t*)g,
      (__attribute__((address_space(3))) uint32_t*)l, 16, 0, 0);
}

// ============ generic tiled f32 GEMM: C[M,N] = A[M,K]@B[K,N] + bias ============
__global__ __launch_bounds__(256) void gemm_bias_kernel(
    const float* __restrict__ A, const float* __restrict__ Bw,
    const float* __restrict__ bias, float* __restrict__ C,
    int M, int N, int K)
{
  __shared__ float As[16][68];
  __shared__ float Bs[16][68];
  const int tid = threadIdx.x;
  const int tx = tid & 15, ty = tid >> 4;
  const int row0 = blockIdx.y * 64;
  const int col0 = blockIdx.x * 64;
  const int alr = tid >> 2, alc = (tid & 3) << 2;
  const int blr = tid >> 4, blc = (tid & 15) << 2;
  float acc[4][4] = {};
  for (int k0 = 0; k0 < K; k0 += 16) {
    const float4 a4 = *reinterpret_cast<const float4*>(&A[(size_t)(row0 + alr) * K + (k0 + alc)]);
    const float4 b4 = *reinterpret_cast<const float4*>(&Bw[(size_t)(k0 + blr) * N + (col0 + blc)]);
    __syncthreads();
    As[alc + 0][alr] = a4.x;
    As[alc + 1][alr] = a4.y;
    As[alc + 2][alr] = a4.z;
    As[alc + 3][alr] = a4.w;
    *reinterpret_cast<float4*>(&Bs[blr][blc]) = b4;
    __syncthreads();
#pragma unroll
    for (int kk = 0; kk < 16; ++kk) {
      const float4 av = *reinterpret_cast<const float4*>(&As[kk][ty << 2]);
      const float4 bv = *reinterpret_cast<const float4*>(&Bs[kk][tx << 2]);
      const float am[4] = {av.x, av.y, av.z, av.w};
      const float bm[4] = {bv.x, bv.y, bv.z, bv.w};
#pragma unroll
      for (int i = 0; i < 4; ++i)
#pragma unroll
        for (int j = 0; j < 4; ++j)
          acc[i][j] = fmaf(am[i], bm[j], acc[i][j]);
    }
  }
#pragma unroll
  for (int i = 0; i < 4; ++i) {
    const int r = row0 + (ty << 2) + i;
#pragma unroll
    for (int j = 0; j < 4; ++j) {
      const int c = col0 + (tx << 2) + j;
      C[(size_t)r * N + c] = acc[i][j] + bias[c];
    }
  }
}

// ============ transpose + f32->bf16: WT[n][k] = bf16(W[k][n]) ============
// grid (N/32, K/32, batch), block 256
__global__ __launch_bounds__(256) void transpose_to_bf16(
    const float* __restrict__ W, short* __restrict__ WT, int K, int N)
{
  const size_t off = (size_t)blockIdx.z * (size_t)K * N;
  const float* Wp = W + off;
  short* WTp = WT + off;
  __shared__ float t[32][33];
  const int tid = threadIdx.x;
  const int tx = tid & 31, ty = tid >> 5;   // ty 0..7
  const int n0 = blockIdx.x * 32, k0 = blockIdx.y * 32;
#pragma unroll
  for (int r = 0; r < 4; ++r)
    t[ty + r * 8][tx] = Wp[(size_t)(k0 + ty + r * 8) * N + n0 + tx];
  __syncthreads();
#pragma unroll
  for (int r = 0; r < 4; ++r)
    WTp[(size_t)(n0 + ty + r * 8) * K + k0 + tx] = f2bf(t[tx][ty + r * 8]);
}

// ============ elementwise f32->bf16 (4/thread) ============
__global__ __launch_bounds__(256) void convert_bf16(
    const float* __restrict__ X, short* __restrict__ Y, int n4)
{
  const int i = blockIdx.x * 256 + threadIdx.x;
  if (i >= n4) return;
  const float4 v = ((const float4*)X)[i];
  s16x4 s;
  s[0] = f2bf(v.x); s[1] = f2bf(v.y); s[2] = f2bf(v.z); s[3] = f2bf(v.w);
  ((s16x4*)Y)[i] = s;
}

// ============ MFMA expert up-proj ============
// inter_bf[tok] = bf16(gelu(Abf[tok] @ Wi[e] + bi[e]))
// Abf [TOKS][HDIM] bf16 (rows gathered via perm); WiT [e][FDIM][HDIM] bf16 (K-contig).
// tile 128x128, BK=32, 256 thr = 4 waves (2x2); fragment-ordered LDS via global_load_lds.
__global__ __launch_bounds__(256) void expert_up_mfma(
    const short* __restrict__ Abf, const short* __restrict__ WiT,
    const float* __restrict__ bi, const int* __restrict__ perm,
    const int* __restrict__ offs, short* __restrict__ interb)
{
  const int e = blockIdx.z;
  const int seg_start = offs[e], seg_end = offs[e + 1];
  const int row0 = seg_start + blockIdx.x * 128;
  if (row0 >= seg_end) return;
  __shared__ __align__(16) short lA[8 * 512];   // [m_tile][lane][8 bf16]
  __shared__ __align__(16) short lB[8 * 512];   // [n_tile][lane][8 bf16]
  __shared__ int toks[128];
  const int tid = threadIdx.x;
  const int w = tid >> 6, lane = tid & 63;
  const int wr = w >> 1, wc = w & 1;
  const int col0 = blockIdx.y * 128;
  if (tid < 128) {
    const int rr = row0 + tid;
    toks[tid] = (rr < seg_end) ? perm[rr] : -1;
  }
  __syncthreads();
  const int sr = lane & 15, kg = lane >> 4;   // frag row/col, k-group
  int t0 = toks[2 * w * 16 + sr];        if (t0 < 0) t0 = toks[0];
  int t1 = toks[(2 * w + 1) * 16 + sr];  if (t1 < 0) t1 = toks[0];
  const short* pa0 = Abf + (size_t)t0 * HDIM + kg * 8;
  const short* pa1 = Abf + (size_t)t1 * HDIM + kg * 8;
  const short* Bt = WiT + (size_t)e * FDIM * HDIM;
  const short* pb0 = Bt + (size_t)(col0 + 2 * w * 16 + sr) * HDIM + kg * 8;
  const short* pb1 = pb0 + (size_t)16 * HDIM;
  short* dA0 = &lA[(2 * w) * 512];
  short* dA1 = &lA[(2 * w + 1) * 512];
  short* dB0 = &lB[(2 * w) * 512];
  short* dB1 = &lB[(2 * w + 1) * 512];
  f32x4 acc[4][4] = {};
  for (int k0 = 0; k0 < HDIM; k0 += 32) {
    gload16(pa0 + k0, dA0);
    gload16(pa1 + k0, dA1);
    gload16(pb0 + k0, dB0);
    gload16(pb1 + k0, dB1);
    __syncthreads();   // vmcnt(0) drained by compiler before barrier -> data visible
    s16x8 af[4], bg[4];
#pragma unroll
    for (int i = 0; i < 4; ++i) {
      af[i] = *(const s16x8*)&lA[(wr * 4 + i) * 512 + lane * 8];
      bg[i] = *(const s16x8*)&lB[(wc * 4 + i) * 512 + lane * 8];
    }
#pragma unroll
    for (int mi = 0; mi < 4; ++mi)
#pragma unroll
      for (int ni = 0; ni < 4; ++ni)
        acc[mi][ni] = __builtin_amdgcn_mfma_f32_16x16x32_bf16(af[mi], bg[ni], acc[mi][ni], 0, 0, 0);
    __syncthreads();   // all waves consumed LDS before next stage overwrites
  }
  const int cl = lane & 15, rg = lane >> 4;
#pragma unroll
  for (int mi = 0; mi < 4; ++mi) {
#pragma unroll
    for (int r = 0; r < 4; ++r) {
      const int rl = wr * 64 + mi * 16 + rg * 4 + r;   // C/D: row=(lane>>4)*4+reg, col=lane&15
      const int tok = toks[rl];
      if (tok < 0) continue;
#pragma unroll
      for (int ni = 0; ni < 4; ++ni) {
        const int c = col0 + wc * 64 + ni * 16 + cl;
        float v = acc[mi][ni][r] + bi[(size_t)e * FDIM + c];
        v = 0.5f * v * (1.0f + erff(v * 0.70710678118654752f));
        interb[(size_t)tok * FDIM + c] = f2bf(v);
      }
    }
  }
}

// ============ MFMA down-proj: C[M=TOKS][N=HDIM] = interb @ Wo + bo ============
// interb [TOKS][FDIM] bf16, WoT [HDIM][FDIM] bf16 (K-contig). Same structure.
__global__ __launch_bounds__(256) void wo_mfma(
    const short* __restrict__ Ab, const short* __restrict__ BT,
    const float* __restrict__ bias, float* __restrict__ C)
{
  __shared__ __align__(16) short lA[8 * 512];
  __shared__ __align__(16) short lB[8 * 512];
  const int tid = threadIdx.x;
  const int w = tid >> 6, lane = tid & 63;
  const int wr = w >> 1, wc = w & 1;
  const int row0 = blockIdx.y * 128, col0 = blockIdx.x * 128;
  const int sr = lane & 15, kg = lane >> 4;
  const short* pa0 = Ab + (size_t)(row0 + 2 * w * 16 + sr) * FDIM + kg * 8;
  const short* pa1 = pa0 + (size_t)16 * FDIM;
  const short* pb0 = BT + (size_t)(col0 + 2 * w * 16 + sr) * FDIM + kg * 8;
  const short* pb1 = pb0 + (size_t)16 * FDIM;
  short* dA0 = &lA[(2 * w) * 512];
  short* dA1 = &lA[(2 * w + 1) * 512];
  short* dB0 = &lB[(2 * w) * 512];
  short* dB1 = &lB[(2 * w + 1) * 512];
  f32x4 acc[4][4] = {};
  for (int k0 = 0; k0 < FDIM; k0 += 32) {
    gload16(pa0 + k0, dA0);
    gload16(pa1 + k0, dA1);
    gload16(pb0 + k0, dB0);
    gload16(pb1 + k0, dB1);
    __syncthreads();
    s16x8 af[4], bg[4];
#pragma unroll
    for (int i = 0; i < 4; ++i) {
      af[i] = *(const s16x8*)&lA[(wr * 4 + i) * 512 + lane * 8];
      bg[i] = *(const s16x8*)&lB[(wc * 4 + i) * 512 + lane * 8];
    }
#pragma unroll
    for (int mi = 0; mi < 4; ++mi)
#pragma unroll
      for (int ni = 0; ni < 4; ++ni)
        acc[mi][ni] = __builtin_amdgcn_mfma_f32_16x16x32_bf16(af[mi], bg[ni], acc[mi][ni], 0, 0, 0);
    __syncthreads();
  }
  const int cl = lane & 15, rg = lane >> 4;
#pragma unroll
  for (int mi = 0; mi < 4; ++mi) {
#pragma unroll
    for (int r = 0; r < 4; ++r) {
      const int row = row0 + wr * 64 + mi * 16 + rg * 4 + r;
#pragma unroll
      for (int ni = 0; ni < 4; ++ni) {
        const int c = col0 + wc * 64 + ni * 16 + cl;
        C[(size_t)row * HDIM + c] = acc[mi][ni][r] + bias[c];
      }
    }
  }
}

// ============ flash attention: non-causal, DH=64 (f32, unchanged) ============
__global__ __launch_bounds__(256) void attention_kernel(
    const float* __restrict__ Q, const float* __restrict__ K,
    const float* __restrict__ V, float* __restrict__ ctx)
{
  __shared__ float QtT[64][68];
  __shared__ float KtT[64][68];
  __shared__ float Vt[64][68];
  __shared__ float StT[64][68];
  __shared__ float mrow[64], lrow[64], crow[64];
  const int tid = threadIdx.x;
  const int tx = tid & 15, ty = tid >> 4;
  const int b = blockIdx.z, h = blockIdx.y;
  const int q0 = blockIdx.x * 64;
  const size_t base = (size_t)b * SEQ * HDIM + (size_t)h * 64;
  const int lr = tid >> 2, lc = (tid & 3) << 2;
#pragma unroll
  for (int d0 = 0; d0 < 64; d0 += 16) {
    const float4 q4 = *reinterpret_cast<const float4*>(
        &Q[base + (size_t)(q0 + lr) * HDIM + d0 + lc]);
    QtT[d0 + lc + 0][lr] = q4.x * 0.125f;
    QtT[d0 + lc + 1][lr] = q4.y * 0.125f;
    QtT[d0 + lc + 2][lr] = q4.z * 0.125f;
    QtT[d0 + lc + 3][lr] = q4.w * 0.125f;
  }
  if (tid < 64) { mrow[tid] = -3.0e38f; lrow[tid] = 0.f; }
  float o[4][4] = {};
  for (int kt = 0; kt < SEQ; kt += 64) {
    float4 k4[4], v4[4];
#pragma unroll
    for (int c = 0; c < 4; ++c) {
      k4[c] = *reinterpret_cast<const float4*>(
          &K[base + (size_t)(kt + lr) * HDIM + c * 16 + lc]);
      v4[c] = *reinterpret_cast<const float4*>(
          &V[base + (size_t)(kt + lr) * HDIM + c * 16 + lc]);
    }
    __syncthreads();
#pragma unroll
    for (int c = 0; c < 4; ++c) {
      KtT[c * 16 + lc + 0][lr] = k4[c].x;
      KtT[c * 16 + lc + 1][lr] = k4[c].y;
      KtT[c * 16 + lc + 2][lr] = k4[c].z;
      KtT[c * 16 + lc + 3][lr] = k4[c].w;
      *reinterpret_cast<float4*>(&Vt[lr][c * 16 + lc]) = v4[c];
    }
    __syncthreads();
    float s[4][4] = {};
#pragma unroll
    for (int d = 0; d < 64; ++d) {
      const float4 qv = *reinterpret_cast<const float4*>(&QtT[d][ty << 2]);
      const float4 kv = *reinterpret_cast<const float4*>(&KtT[d][tx << 2]);
      const float qa[4] = {qv.x, qv.y, qv.z, qv.w};
      const float kb[4] = {kv.x, kv.y, kv.z, kv.w};
#pragma unroll
      for (int i = 0; i < 4; ++i)
#pragma unroll
        for (int j = 0; j < 4; ++j)
          s[i][j] = fmaf(qa[i], kb[j], s[i][j]);
    }
#pragma unroll
    for (int i = 0; i < 4; ++i)
#pragma unroll
      for (int j = 0; j < 4; ++j)
        StT[(tx << 2) + j][(ty << 2) + i] = s[i][j];
    __syncthreads();
    {
      const int r = tid >> 2, sl = tid & 3;
      const float m_old = mrow[r];
      float mx = m_old;
#pragma unroll
      for (int k2 = sl * 16; k2 < sl * 16 + 16; ++k2) mx = fmaxf(mx, StT[k2][r]);
      mx = fmaxf(mx, __shfl_xor(mx, 1));
      mx = fmaxf(mx, __shfl_xor(mx, 2));
      float sum = 0.f;
#pragma unroll
      for (int k2 = sl * 16; k2 < sl * 16 + 16; ++k2) {
        const float p = expf(StT[k2][r] - mx);
        StT[k2][r] = p;
        sum += p;
      }
      sum += __shfl_xor(sum, 1);
      sum += __shfl_xor(sum, 2);
      if (sl == 0) {
        const float corr = expf(m_old - mx);
        crow[r] = corr;
        lrow[r] = lrow[r] * corr + sum;
        mrow[r] = mx;
      }
    }
    __syncthreads();
    float cf[4];
#pragma unroll
    for (int i = 0; i < 4; ++i) cf[i] = crow[(ty << 2) + i];
#pragma unroll
    for (int i = 0; i < 4; ++i)
#pragma unroll
      for (int j = 0; j < 4; ++j) o[i][j] *= cf[i];
#pragma unroll
    for (int k2 = 0; k2 < 64; ++k2) {
      const float4 pv = *reinterpret_cast<const float4*>(&StT[k2][ty << 2]);
      const float4 vv = *reinterpret_cast<const float4*>(&Vt[k2][tx << 2]);
      const float pa[4] = {pv.x, pv.y, pv.z, pv.w};
      const float vb[4] = {vv.x, vv.y, vv.z, vv.w};
#pragma unroll
      for (int i = 0; i < 4; ++i)
#pragma unroll
        for (int j = 0; j < 4; ++j)
          o[i][j] = fmaf(pa[i], vb[j], o[i][j]);
    }
  }
#pragma unroll
  for (int i = 0; i < 4; ++i) {
    const int r = (ty << 2) + i;
    const float inv = 1.f / lrow[r];
#pragma unroll
    for (int j = 0; j < 4; ++j)
      ctx[base + (size_t)(q0 + r) * HDIM + (tx << 2) + j] = o[i][j] * inv;
  }
}

// ============ residual add + LayerNorm (unchanged) ============
__global__ __launch_bounds__(256) void add_ln_kernel(
    const float* __restrict__ X, const float* __restrict__ R,
    const float* __restrict__ g, const float* __restrict__ bb,
    float* __restrict__ out)
{
  const int t = blockIdx.x;
  const int tid = threadIdx.x;
  const float* x = X + (size_t)t * HDIM;
  const float* r = R + (size_t)t * HDIM;
  float v[3];
  float sum = 0.f, ssq = 0.f;
#pragma unroll
  for (int i = 0; i < 3; ++i) {
    const float val = x[tid + i * 256] + r[tid + i * 256];
    v[i] = val;
    sum += val;
    ssq += val * val;
  }
#pragma unroll
  for (int o = 32; o > 0; o >>= 1) {
    sum += __shfl_down(sum, o);
    ssq += __shfl_down(ssq, o);
  }
  __shared__ float red[10];
  const int wid = tid >> 6, lane = tid & 63;
  if (lane == 0) { red[wid] = sum; red[4 + wid] = ssq; }
  __syncthreads();
  if (tid == 0) {
    const float s = red[0] + red[1] + red[2] + red[3];
    const float q = red[4] + red[5] + red[6] + red[7];
    const float mean = s * (1.f / HDIM);
    const float var = q * (1.f / HDIM) - mean * mean;
    red[8] = mean;
    red[9] = rsqrtf(fmaxf(var, 0.f) + 1e-12f);
  }
  __syncthreads();
  const float mean = red[8], rstd = red[9];
#pragma unroll
  for (int i = 0; i < 3; ++i) {
    const int idx = tid + i * 256;
    out[(size_t)t * HDIM + idx] = g[idx] * (v[i] - mean) * rstd + bb[idx];
  }
}

// ============ router (unchanged, f32 — keeps argmax bit-identical) ============
__global__ __launch_bounds__(256) void router_kernel(
    const float* __restrict__ X, const float* __restrict__ Wr,
    const float* __restrict__ br, float* __restrict__ scores_out,
    int* __restrict__ expert, int* __restrict__ counts)
{
  const int wid = threadIdx.x >> 6, lane = threadIdx.x & 63;
  const int tok = blockIdx.x * 4 + wid;
  const float* x = X + (size_t)tok * HDIM;
  float acc[8] = {};
  for (int k0 = 0; k0 < HDIM; k0 += 64) {
    const float xv = x[k0 + lane];
    const float* wrow = Wr + (size_t)(k0 + lane) * NEXP;
    const float4 w0 = *reinterpret_cast<const float4*>(wrow);
    const float4 w1 = *reinterpret_cast<const float4*>(wrow + 4);
    acc[0] = fmaf(xv, w0.x, acc[0]);
    acc[1] = fmaf(xv, w0.y, acc[1]);
    acc[2] = fmaf(xv, w0.z, acc[2]);
    acc[3] = fmaf(xv, w0.w, acc[3]);
    acc[4] = fmaf(xv, w1.x, acc[4]);
    acc[5] = fmaf(xv, w1.y, acc[5]);
    acc[6] = fmaf(xv, w1.z, acc[6]);
    acc[7] = fmaf(xv, w1.w, acc[7]);
  }
#pragma unroll
  for (int e = 0; e < 8; ++e)
#pragma unroll
    for (int o = 32; o > 0; o >>= 1) acc[e] += __shfl_down(acc[e], o);
  if (lane == 0) {
    float mx = -3.0e38f;
#pragma unroll
    for (int e = 0; e < 8; ++e) { acc[e] += br[e]; mx = fmaxf(mx, acc[e]); }
    float sum = 0.f;
#pragma unroll
    for (int e = 0; e < 8; ++e) { acc[e] = expf(acc[e] - mx); sum += acc[e]; }
    const float inv = 1.f / sum;
    int best = 0;
    float bv = acc[0];
#pragma unroll
    for (int e = 0; e < 8; ++e) {
      const float p = acc[e] * inv;
      scores_out[(size_t)tok * NEXP + e] = p;
      if (acc[e] > bv) { bv = acc[e]; best = e; }
    }
    expert[tok] = best;
    atomicAdd(&counts[best], 1);
  }
}

__global__ void offsets_kernel(const int* __restrict__ counts, int* __restrict__ offs)
{
  if (threadIdx.x == 0 && blockIdx.x == 0) {
    int a = 0;
    for (int e = 0; e < NEXP; ++e) { offs[e] = a; a += counts[e]; }
    offs[NEXP] = a;
  }
}

__global__ __launch_bounds__(256) void scatter_kernel(
    const int* __restrict__ expert, const int* __restrict__ offs,
    int* __restrict__ cursor, int* __restrict__ perm)
{
  const int t = blockIdx.x * 256 + threadIdx.x;
  if (t >= TOKS) return;
  const int e = expert[t];
  const int pos = atomicAdd(&cursor[e], 1);
  perm[offs[e] + pos] = t;
}

extern "C" void kernel_launch(void* const* d_in, const int* in_sizes, int n_in,
                              void* d_out, int out_size, void* d_ws, size_t ws_size,
                              hipStream_t stream) {
  const float* hidden = (const float*)d_in[0];
  const float* Wq  = (const float*)d_in[1];
  const float* bq  = (const float*)d_in[2];
  const float* Wk  = (const float*)d_in[3];
  const float* bk  = (const float*)d_in[4];
  const float* Wv  = (const float*)d_in[5];
  const float* bv  = (const float*)d_in[6];
  const float* Wao = (const float*)d_in[7];
  const float* bao = (const float*)d_in[8];
  const float* ln1g = (const float*)d_in[9];
  const float* ln1b = (const float*)d_in[10];
  const float* Wr  = (const float*)d_in[11];
  const float* br  = (const float*)d_in[12];
  const float* Wi  = (const float*)d_in[13];
  const float* bi  = (const float*)d_in[14];
  const float* Wo  = (const float*)d_in[15];
  const float* bo  = (const float*)d_in[16];
  const float* ln2g = (const float*)d_in[17];
  const float* ln2b = (const float*)d_in[18];

  float* out = (float*)d_out;
  float* scores_out = out + (size_t)TOKS * HDIM;

  const size_t M1 = (size_t)TOKS * HDIM;   // 6.29M floats
  float* ws = (float*)d_ws;
  // phase-1 arena (f32):
  float* Qb       = ws;            // [0, M1)
  float* Kb       = ws + M1;       // [M1, 2M1)
  float* Vb       = ws + 2 * M1;   // [2M1, 3M1)   dead after attention
  float* ctxb     = ws + 3 * M1;   // [3M1, 4M1)   dead after AO proj
  float* aoproj   = ws;            // reuse Q
  float* attn_out = ws + M1;       // live to the end
  float* tmp2     = ws;            // final down-proj output (f32)
  // phase-2 region R at [2M1, ...): written only AFTER Vb/ctxb are dead
  short* Abf    = (short*)(ws + 2 * M1);                 // TOKS*HDIM bf16
  short* WiT    = (short*)(ws + 2 * M1 + M1 / 2);        // NEXP*FDIM*HDIM bf16
  short* WoT    = WiT + (size_t)NEXP * FDIM * HDIM;      // HDIM*FDIM bf16
  short* interb = WoT + (size_t)HDIM * FDIM;             // TOKS*FDIM bf16
  int* ints   = (int*)(interb + (size_t)TOKS * FDIM);
  int* perm   = ints;
  int* expert = ints + TOKS;
  int* counts = expert + TOKS;
  int* offs   = counts + NEXP;
  int* cursor = offs + NEXP + 1;

  hipMemsetAsync(counts, 0, (NEXP + NEXP + 1 + NEXP) * sizeof(int), stream);

  const dim3 blk(256);
  const dim3 g_h(HDIM / 64, TOKS / 64);   // (12,128)
  gemm_bias_kernel<<<g_h, blk, 0, stream>>>(hidden, Wq, bq, Qb, TOKS, HDIM, HDIM);
  gemm_bias_kernel<<<g_h, blk, 0, stream>>>(hidden, Wk, bk, Kb, TOKS, HDIM, HDIM);
  gemm_bias_kernel<<<g_h, blk, 0, stream>>>(hidden, Wv, bv, Vb, TOKS, HDIM, HDIM);

  attention_kernel<<<dim3(SEQ / 64, NHEAD, BATCH), blk, 0, stream>>>(Qb, Kb, Vb, ctxb);

  gemm_bias_kernel<<<g_h, blk, 0, stream>>>(ctxb, Wao, bao, aoproj, TOKS, HDIM, HDIM);
  add_ln_kernel<<<dim3(TOKS), blk, 0, stream>>>(aoproj, hidden, ln1g, ln1b, attn_out);

  router_kernel<<<dim3(TOKS / 4), blk, 0, stream>>>(attn_out, Wr, br, scores_out, expert, counts);
  offsets_kernel<<<dim3(1), dim3(64), 0, stream>>>(counts, offs);
  scatter_kernel<<<dim3(TOKS / 256), blk, 0, stream>>>(expert, offs, cursor, perm);

  // bf16 prep (Vb/ctxb dead now): weights transposed K-contig, activations converted
  transpose_to_bf16<<<dim3(FDIM / 32, HDIM / 32, NEXP), blk, 0, stream>>>(Wi, WiT, HDIM, FDIM);
  transpose_to_bf16<<<dim3(HDIM / 32, FDIM / 32, 1), blk, 0, stream>>>(Wo, WoT, FDIM, HDIM);
  convert_bf16<<<dim3((TOKS * HDIM / 4 + 255) / 256), blk, 0, stream>>>(attn_out, Abf, TOKS * HDIM / 4);

  expert_up_mfma<<<dim3(TOKS / 128, FDIM / 128, NEXP), blk, 0, stream>>>(
      Abf, WiT, bi, perm, offs, interb);

  wo_mfma<<<dim3(HDIM / 128, TOKS / 128), blk, 0, stream>>>(interb, WoT, bo, tmp2);

  add_ln_kernel<<<dim3(TOKS), blk, 0, stream>>>(tmp2, attn_out, ln2g, ln2b, out);
}

// Round 5
// 1357.293 us; speedup vs baseline: 1.9264x; 1.2933x over previous
//
#include <hip/hip_runtime.h>
#include <math.h>
#include <stdint.h>

#define TOKS 8192
#define HDIM 768
#define FDIM 3072
#define NEXP 8
#define NHEAD 12
#define SEQ 1024
#define BATCH 8
#define QKVSTR 2304   // fused Q|K|V row stride

typedef __attribute__((ext_vector_type(8))) short s16x8;   // 8 bf16 = 4 VGPR
typedef __attribute__((ext_vector_type(4))) short s16x4;
typedef __attribute__((ext_vector_type(4))) float f32x4;

__device__ __forceinline__ short f2bf(float f) {
  uint32_t u = __float_as_uint(f);
  uint32_t r = (u + 0x7fffu + ((u >> 16) & 1u)) >> 16;   // RTN-even
  return (short)(r & 0xffffu);
}
__device__ __forceinline__ float bf2f(short h) {
  return __uint_as_float(((uint32_t)(uint16_t)h) << 16);
}
__device__ __forceinline__ void gload16(const void* g, void* l) {
  __builtin_amdgcn_global_load_lds(
      (const __attribute__((address_space(1))) uint32_t*)g,
      (__attribute__((address_space(3))) uint32_t*)l, 16, 0, 0);
}

// ============ f32 -> (hi,lo) bf16 split, 4 elems/thread ============
__global__ __launch_bounds__(256) void convert_split(
    const float* __restrict__ X, short* __restrict__ Xh, short* __restrict__ Xl, int n4)
{
  const int i = blockIdx.x * 256 + threadIdx.x;
  if (i >= n4) return;
  const float4 v = ((const float4*)X)[i];
  const float a[4] = {v.x, v.y, v.z, v.w};
  s16x4 h, l;
#pragma unroll
  for (int j = 0; j < 4; ++j) {
    h[j] = f2bf(a[j]);
    l[j] = f2bf(a[j] - bf2f(h[j]));
  }
  ((s16x4*)Xh)[i] = h;
  ((s16x4*)Xl)[i] = l;
}

// ============ transpose + split: WT{h,l}[n][k] = split(W[k][n]) ============
// grid (N/32, K/32), block 256
__global__ __launch_bounds__(256) void transpose_split(
    const float* __restrict__ W, short* __restrict__ WTh, short* __restrict__ WTl,
    int K, int N)
{
  __shared__ float t[32][33];
  const int tid = threadIdx.x;
  const int tx = tid & 31, ty = tid >> 5;
  const int n0 = blockIdx.x * 32, k0 = blockIdx.y * 32;
#pragma unroll
  for (int r = 0; r < 4; ++r)
    t[ty + r * 8][tx] = W[(size_t)(k0 + ty + r * 8) * N + n0 + tx];
  __syncthreads();
#pragma unroll
  for (int r = 0; r < 4; ++r) {
    const float v = t[tx][ty + r * 8];
    const short h = f2bf(v);
    WTh[(size_t)(n0 + ty + r * 8) * K + k0 + tx] = h;
    WTl[(size_t)(n0 + ty + r * 8) * K + k0 + tx] = f2bf(v - bf2f(h));
  }
}

// ============ split-bf16 MFMA GEMM: C = (Ah+Al)@(Bh+Bl)^T + bias, f32 out ============
// A{h,l} [M][K] bf16, B{h,l}T [N][K] bf16. 128x128 tile, BK=32, 4 waves.
// 3 products: AhBh + AhBl + AlBh (AlBl ~2^-18, dropped).
__global__ __launch_bounds__(256) void gemm_split_mfma(
    const short* __restrict__ Ah, const short* __restrict__ Al,
    const short* __restrict__ BhT, const short* __restrict__ BlT,
    const float* __restrict__ bias, float* __restrict__ C,
    int N, int K)
{
  __shared__ __align__(16) short lAh[8 * 512];
  __shared__ __align__(16) short lAl[8 * 512];
  __shared__ __align__(16) short lBh[8 * 512];
  __shared__ __align__(16) short lBl[8 * 512];
  const int tid = threadIdx.x;
  const int w = tid >> 6, lane = tid & 63;
  const int wr = w >> 1, wc = w & 1;
  const int row0 = blockIdx.y * 128, col0 = blockIdx.x * 128;
  const int sr = lane & 15, kg = lane >> 4;
  const size_t a0 = (size_t)(row0 + 2 * w * 16 + sr) * K + kg * 8;
  const size_t a1 = a0 + (size_t)16 * K;
  const size_t b0 = (size_t)(col0 + 2 * w * 16 + sr) * K + kg * 8;
  const size_t b1 = b0 + (size_t)16 * K;
  short* dAh0 = &lAh[(2 * w) * 512]; short* dAh1 = dAh0 + 512;
  short* dAl0 = &lAl[(2 * w) * 512]; short* dAl1 = dAl0 + 512;
  short* dBh0 = &lBh[(2 * w) * 512]; short* dBh1 = dBh0 + 512;
  short* dBl0 = &lBl[(2 * w) * 512]; short* dBl1 = dBl0 + 512;
  f32x4 acc[4][4] = {};
  for (int k0 = 0; k0 < K; k0 += 32) {
    gload16(Ah + a0 + k0, dAh0);
    gload16(Ah + a1 + k0, dAh1);
    gload16(Al + a0 + k0, dAl0);
    gload16(Al + a1 + k0, dAl1);
    gload16(BhT + b0 + k0, dBh0);
    gload16(BhT + b1 + k0, dBh1);
    gload16(BlT + b0 + k0, dBl0);
    gload16(BlT + b1 + k0, dBl1);
    __syncthreads();
    s16x8 ah[4], al[4], bh[4], bl[4];
#pragma unroll
    for (int i = 0; i < 4; ++i) {
      ah[i] = *(const s16x8*)&lAh[(wr * 4 + i) * 512 + lane * 8];
      al[i] = *(const s16x8*)&lAl[(wr * 4 + i) * 512 + lane * 8];
      bh[i] = *(const s16x8*)&lBh[(wc * 4 + i) * 512 + lane * 8];
      bl[i] = *(const s16x8*)&lBl[(wc * 4 + i) * 512 + lane * 8];
    }
#pragma unroll
    for (int mi = 0; mi < 4; ++mi)
#pragma unroll
      for (int ni = 0; ni < 4; ++ni) {
        acc[mi][ni] = __builtin_amdgcn_mfma_f32_16x16x32_bf16(ah[mi], bh[ni], acc[mi][ni], 0, 0, 0);
        acc[mi][ni] = __builtin_amdgcn_mfma_f32_16x16x32_bf16(ah[mi], bl[ni], acc[mi][ni], 0, 0, 0);
        acc[mi][ni] = __builtin_amdgcn_mfma_f32_16x16x32_bf16(al[mi], bh[ni], acc[mi][ni], 0, 0, 0);
      }
    __syncthreads();
  }
  const int cl = lane & 15, rg = lane >> 4;
#pragma unroll
  for (int mi = 0; mi < 4; ++mi)
#pragma unroll
    for (int r = 0; r < 4; ++r) {
      const int row = row0 + wr * 64 + mi * 16 + rg * 4 + r;
#pragma unroll
      for (int ni = 0; ni < 4; ++ni) {
        const int c = col0 + wc * 64 + ni * 16 + cl;
        C[(size_t)row * N + c] = acc[mi][ni][r] + bias[c];
      }
    }
}

// ============ f32->bf16 elementwise (expert path A) ============
__global__ __launch_bounds__(256) void convert_bf16(
    const float* __restrict__ X, short* __restrict__ Y, int n4)
{
  const int i = blockIdx.x * 256 + threadIdx.x;
  if (i >= n4) return;
  const float4 v = ((const float4*)X)[i];
  s16x4 s;
  s[0] = f2bf(v.x); s[1] = f2bf(v.y); s[2] = f2bf(v.z); s[3] = f2bf(v.w);
  ((s16x4*)Y)[i] = s;
}

// ============ transpose + f32->bf16 (expert weights) ============
__global__ __launch_bounds__(256) void transpose_to_bf16(
    const float* __restrict__ W, short* __restrict__ WT, int K, int N)
{
  const size_t off = (size_t)blockIdx.z * (size_t)K * N;
  const float* Wp = W + off;
  short* WTp = WT + off;
  __shared__ float t[32][33];
  const int tid = threadIdx.x;
  const int tx = tid & 31, ty = tid >> 5;
  const int n0 = blockIdx.x * 32, k0 = blockIdx.y * 32;
#pragma unroll
  for (int r = 0; r < 4; ++r)
    t[ty + r * 8][tx] = Wp[(size_t)(k0 + ty + r * 8) * N + n0 + tx];
  __syncthreads();
#pragma unroll
  for (int r = 0; r < 4; ++r)
    WTp[(size_t)(n0 + ty + r * 8) * K + k0 + tx] = f2bf(t[tx][ty + r * 8]);
}

// ============ MFMA expert up-proj (unchanged from R3) ============
__global__ __launch_bounds__(256) void expert_up_mfma(
    const short* __restrict__ Abf, const short* __restrict__ WiT,
    const float* __restrict__ bi, const int* __restrict__ perm,
    const int* __restrict__ offs, short* __restrict__ interb)
{
  const int e = blockIdx.z;
  const int seg_start = offs[e], seg_end = offs[e + 1];
  const int row0 = seg_start + blockIdx.x * 128;
  if (row0 >= seg_end) return;
  __shared__ __align__(16) short lA[8 * 512];
  __shared__ __align__(16) short lB[8 * 512];
  __shared__ int toks[128];
  const int tid = threadIdx.x;
  const int w = tid >> 6, lane = tid & 63;
  const int wr = w >> 1, wc = w & 1;
  const int col0 = blockIdx.y * 128;
  if (tid < 128) {
    const int rr = row0 + tid;
    toks[tid] = (rr < seg_end) ? perm[rr] : -1;
  }
  __syncthreads();
  const int sr = lane & 15, kg = lane >> 4;
  int t0 = toks[2 * w * 16 + sr];        if (t0 < 0) t0 = toks[0];
  int t1 = toks[(2 * w + 1) * 16 + sr];  if (t1 < 0) t1 = toks[0];
  const short* pa0 = Abf + (size_t)t0 * HDIM + kg * 8;
  const short* pa1 = Abf + (size_t)t1 * HDIM + kg * 8;
  const short* Bt = WiT + (size_t)e * FDIM * HDIM;
  const short* pb0 = Bt + (size_t)(col0 + 2 * w * 16 + sr) * HDIM + kg * 8;
  const short* pb1 = pb0 + (size_t)16 * HDIM;
  short* dA0 = &lA[(2 * w) * 512];
  short* dA1 = &lA[(2 * w + 1) * 512];
  short* dB0 = &lB[(2 * w) * 512];
  short* dB1 = &lB[(2 * w + 1) * 512];
  f32x4 acc[4][4] = {};
  for (int k0 = 0; k0 < HDIM; k0 += 32) {
    gload16(pa0 + k0, dA0);
    gload16(pa1 + k0, dA1);
    gload16(pb0 + k0, dB0);
    gload16(pb1 + k0, dB1);
    __syncthreads();
    s16x8 af[4], bg[4];
#pragma unroll
    for (int i = 0; i < 4; ++i) {
      af[i] = *(const s16x8*)&lA[(wr * 4 + i) * 512 + lane * 8];
      bg[i] = *(const s16x8*)&lB[(wc * 4 + i) * 512 + lane * 8];
    }
#pragma unroll
    for (int mi = 0; mi < 4; ++mi)
#pragma unroll
      for (int ni = 0; ni < 4; ++ni)
        acc[mi][ni] = __builtin_amdgcn_mfma_f32_16x16x32_bf16(af[mi], bg[ni], acc[mi][ni], 0, 0, 0);
    __syncthreads();
  }
  const int cl = lane & 15, rg = lane >> 4;
#pragma unroll
  for (int mi = 0; mi < 4; ++mi) {
#pragma unroll
    for (int r = 0; r < 4; ++r) {
      const int rl = wr * 64 + mi * 16 + rg * 4 + r;
      const int tok = toks[rl];
      if (tok < 0) continue;
#pragma unroll
      for (int ni = 0; ni < 4; ++ni) {
        const int c = col0 + wc * 64 + ni * 16 + cl;
        float v = acc[mi][ni][r] + bi[(size_t)e * FDIM + c];
        v = 0.5f * v * (1.0f + erff(v * 0.70710678118654752f));
        interb[(size_t)tok * FDIM + c] = f2bf(v);
      }
    }
  }
}

// ============ MFMA down-proj (unchanged from R3) ============
__global__ __launch_bounds__(256) void wo_mfma(
    const short* __restrict__ Ab, const short* __restrict__ BT,
    const float* __restrict__ bias, float* __restrict__ C)
{
  __shared__ __align__(16) short lA[8 * 512];
  __shared__ __align__(16) short lB[8 * 512];
  const int tid = threadIdx.x;
  const int w = tid >> 6, lane = tid & 63;
  const int wr = w >> 1, wc = w & 1;
  const int row0 = blockIdx.y * 128, col0 = blockIdx.x * 128;
  const int sr = lane & 15, kg = lane >> 4;
  const short* pa0 = Ab + (size_t)(row0 + 2 * w * 16 + sr) * FDIM + kg * 8;
  const short* pa1 = pa0 + (size_t)16 * FDIM;
  const short* pb0 = BT + (size_t)(col0 + 2 * w * 16 + sr) * FDIM + kg * 8;
  const short* pb1 = pb0 + (size_t)16 * FDIM;
  short* dA0 = &lA[(2 * w) * 512];
  short* dA1 = &lA[(2 * w + 1) * 512];
  short* dB0 = &lB[(2 * w) * 512];
  short* dB1 = &lB[(2 * w + 1) * 512];
  f32x4 acc[4][4] = {};
  for (int k0 = 0; k0 < FDIM; k0 += 32) {
    gload16(pa0 + k0, dA0);
    gload16(pa1 + k0, dA1);
    gload16(pb0 + k0, dB0);
    gload16(pb1 + k0, dB1);
    __syncthreads();
    s16x8 af[4], bg[4];
#pragma unroll
    for (int i = 0; i < 4; ++i) {
      af[i] = *(const s16x8*)&lA[(wr * 4 + i) * 512 + lane * 8];
      bg[i] = *(const s16x8*)&lB[(wc * 4 + i) * 512 + lane * 8];
    }
#pragma unroll
    for (int mi = 0; mi < 4; ++mi)
#pragma unroll
      for (int ni = 0; ni < 4; ++ni)
        acc[mi][ni] = __builtin_amdgcn_mfma_f32_16x16x32_bf16(af[mi], bg[ni], acc[mi][ni], 0, 0, 0);
    __syncthreads();
  }
  const int cl = lane & 15, rg = lane >> 4;
#pragma unroll
  for (int mi = 0; mi < 4; ++mi) {
#pragma unroll
    for (int r = 0; r < 4; ++r) {
      const int row = row0 + wr * 64 + mi * 16 + rg * 4 + r;
#pragma unroll
      for (int ni = 0; ni < 4; ++ni) {
        const int c = col0 + wc * 64 + ni * 16 + cl;
        C[(size_t)row * HDIM + c] = acc[mi][ni][r] + bias[c];
      }
    }
  }
}

// ============ flash attention (f32; reads fused QKV with stride 2304) ============
__global__ __launch_bounds__(256) void attention_kernel(
    const float* __restrict__ QKV, float* __restrict__ ctx)
{
  __shared__ float QtT[64][68];
  __shared__ float KtT[64][68];
  __shared__ float Vt[64][68];
  __shared__ float StT[64][68];
  __shared__ float mrow[64], lrow[64], crow[64];
  const int tid = threadIdx.x;
  const int tx = tid & 15, ty = tid >> 4;
  const int b = blockIdx.z, h = blockIdx.y;
  const int q0 = blockIdx.x * 64;
  const size_t rb = (size_t)b * SEQ;
  const float* Qp = QKV + (size_t)h * 64;
  const float* Kp = Qp + HDIM;
  const float* Vp = Qp + 2 * HDIM;
  const size_t baseC = rb * HDIM + (size_t)h * 64;
  const int lr = tid >> 2, lc = (tid & 3) << 2;
#pragma unroll
  for (int d0 = 0; d0 < 64; d0 += 16) {
    const float4 q4 = *reinterpret_cast<const float4*>(
        &Qp[(rb + q0 + lr) * QKVSTR + d0 + lc]);
    QtT[d0 + lc + 0][lr] = q4.x * 0.125f;
    QtT[d0 + lc + 1][lr] = q4.y * 0.125f;
    QtT[d0 + lc + 2][lr] = q4.z * 0.125f;
    QtT[d0 + lc + 3][lr] = q4.w * 0.125f;
  }
  if (tid < 64) { mrow[tid] = -3.0e38f; lrow[tid] = 0.f; }
  float o[4][4] = {};
  for (int kt = 0; kt < SEQ; kt += 64) {
    float4 k4[4], v4[4];
#pragma unroll
    for (int c = 0; c < 4; ++c) {
      k4[c] = *reinterpret_cast<const float4*>(
          &Kp[(rb + kt + lr) * QKVSTR + c * 16 + lc]);
      v4[c] = *reinterpret_cast<const float4*>(
          &Vp[(rb + kt + lr) * QKVSTR + c * 16 + lc]);
    }
    __syncthreads();
#pragma unroll
    for (int c = 0; c < 4; ++c) {
      KtT[c * 16 + lc + 0][lr] = k4[c].x;
      KtT[c * 16 + lc + 1][lr] = k4[c].y;
      KtT[c * 16 + lc + 2][lr] = k4[c].z;
      KtT[c * 16 + lc + 3][lr] = k4[c].w;
      *reinterpret_cast<float4*>(&Vt[lr][c * 16 + lc]) = v4[c];
    }
    __syncthreads();
    float s[4][4] = {};
#pragma unroll
    for (int d = 0; d < 64; ++d) {
      const float4 qv = *reinterpret_cast<const float4*>(&QtT[d][ty << 2]);
      const float4 kv = *reinterpret_cast<const float4*>(&KtT[d][tx << 2]);
      const float qa[4] = {qv.x, qv.y, qv.z, qv.w};
      const float kb[4] = {kv.x, kv.y, kv.z, kv.w};
#pragma unroll
      for (int i = 0; i < 4; ++i)
#pragma unroll
        for (int j = 0; j < 4; ++j)
          s[i][j] = fmaf(qa[i], kb[j], s[i][j]);
    }
#pragma unroll
    for (int i = 0; i < 4; ++i)
#pragma unroll
      for (int j = 0; j < 4; ++j)
        StT[(tx << 2) + j][(ty << 2) + i] = s[i][j];
    __syncthreads();
    {
      const int r = tid >> 2, sl = tid & 3;
      const float m_old = mrow[r];
      float mx = m_old;
#pragma unroll
      for (int k2 = sl * 16; k2 < sl * 16 + 16; ++k2) mx = fmaxf(mx, StT[k2][r]);
      mx = fmaxf(mx, __shfl_xor(mx, 1));
      mx = fmaxf(mx, __shfl_xor(mx, 2));
      float sum = 0.f;
#pragma unroll
      for (int k2 = sl * 16; k2 < sl * 16 + 16; ++k2) {
        const float p = expf(StT[k2][r] - mx);
        StT[k2][r] = p;
        sum += p;
      }
      sum += __shfl_xor(sum, 1);
      sum += __shfl_xor(sum, 2);
      if (sl == 0) {
        const float corr = expf(m_old - mx);
        crow[r] = corr;
        lrow[r] = lrow[r] * corr + sum;
        mrow[r] = mx;
      }
    }
    __syncthreads();
    float cf[4];
#pragma unroll
    for (int i = 0; i < 4; ++i) cf[i] = crow[(ty << 2) + i];
#pragma unroll
    for (int i = 0; i < 4; ++i)
#pragma unroll
      for (int j = 0; j < 4; ++j) o[i][j] *= cf[i];
#pragma unroll
    for (int k2 = 0; k2 < 64; ++k2) {
      const float4 pv = *reinterpret_cast<const float4*>(&StT[k2][ty << 2]);
      const float4 vv = *reinterpret_cast<const float4*>(&Vt[k2][tx << 2]);
      const float pa[4] = {pv.x, pv.y, pv.z, pv.w};
      const float vb[4] = {vv.x, vv.y, vv.z, vv.w};
#pragma unroll
      for (int i = 0; i < 4; ++i)
#pragma unroll
        for (int j = 0; j < 4; ++j)
          o[i][j] = fmaf(pa[i], vb[j], o[i][j]);
    }
  }
#pragma unroll
  for (int i = 0; i < 4; ++i) {
    const int r = (ty << 2) + i;
    const float inv = 1.f / lrow[r];
#pragma unroll
    for (int j = 0; j < 4; ++j)
      ctx[baseC + (size_t)(q0 + r) * HDIM + (tx << 2) + j] = o[i][j] * inv;
  }
}

// ============ residual add + LayerNorm (unchanged) ============
__global__ __launch_bounds__(256) void add_ln_kernel(
    const float* __restrict__ X, const float* __restrict__ R,
    const float* __restrict__ g, const float* __restrict__ bb,
    float* __restrict__ out)
{
  const int t = blockIdx.x;
  const int tid = threadIdx.x;
  const float* x = X + (size_t)t * HDIM;
  const float* r = R + (size_t)t * HDIM;
  float v[3];
  float sum = 0.f, ssq = 0.f;
#pragma unroll
  for (int i = 0; i < 3; ++i) {
    const float val = x[tid + i * 256] + r[tid + i * 256];
    v[i] = val;
    sum += val;
    ssq += val * val;
  }
#pragma unroll
  for (int o = 32; o > 0; o >>= 1) {
    sum += __shfl_down(sum, o);
    ssq += __shfl_down(ssq, o);
  }
  __shared__ float red[10];
  const int wid = tid >> 6, lane = tid & 63;
  if (lane == 0) { red[wid] = sum; red[4 + wid] = ssq; }
  __syncthreads();
  if (tid == 0) {
    const float s = red[0] + red[1] + red[2] + red[3];
    const float q = red[4] + red[5] + red[6] + red[7];
    const float mean = s * (1.f / HDIM);
    const float var = q * (1.f / HDIM) - mean * mean;
    red[8] = mean;
    red[9] = rsqrtf(fmaxf(var, 0.f) + 1e-12f);
  }
  __syncthreads();
  const float mean = red[8], rstd = red[9];
#pragma unroll
  for (int i = 0; i < 3; ++i) {
    const int idx = tid + i * 256;
    out[(size_t)t * HDIM + idx] = g[idx] * (v[i] - mean) * rstd + bb[idx];
  }
}

// ============ router (unchanged, f32) ============
__global__ __launch_bounds__(256) void router_kernel(
    const float* __restrict__ X, const float* __restrict__ Wr,
    const float* __restrict__ br, float* __restrict__ scores_out,
    int* __restrict__ expert, int* __restrict__ counts)
{
  const int wid = threadIdx.x >> 6, lane = threadIdx.x & 63;
  const int tok = blockIdx.x * 4 + wid;
  const float* x = X + (size_t)tok * HDIM;
  float acc[8] = {};
  for (int k0 = 0; k0 < HDIM; k0 += 64) {
    const float xv = x[k0 + lane];
    const float* wrow = Wr + (size_t)(k0 + lane) * NEXP;
    const float4 w0 = *reinterpret_cast<const float4*>(wrow);
    const float4 w1 = *reinterpret_cast<const float4*>(wrow + 4);
    acc[0] = fmaf(xv, w0.x, acc[0]);
    acc[1] = fmaf(xv, w0.y, acc[1]);
    acc[2] = fmaf(xv, w0.z, acc[2]);
    acc[3] = fmaf(xv, w0.w, acc[3]);
    acc[4] = fmaf(xv, w1.x, acc[4]);
    acc[5] = fmaf(xv, w1.y, acc[5]);
    acc[6] = fmaf(xv, w1.z, acc[6]);
    acc[7] = fmaf(xv, w1.w, acc[7]);
  }
#pragma unroll
  for (int e = 0; e < 8; ++e)
#pragma unroll
    for (int o = 32; o > 0; o >>= 1) acc[e] += __shfl_down(acc[e], o);
  if (lane == 0) {
    float mx = -3.0e38f;
#pragma unroll
    for (int e = 0; e < 8; ++e) { acc[e] += br[e]; mx = fmaxf(mx, acc[e]); }
    float sum = 0.f;
#pragma unroll
    for (int e = 0; e < 8; ++e) { acc[e] = expf(acc[e] - mx); sum += acc[e]; }
    const float inv = 1.f / sum;
    int best = 0;
    float bv = acc[0];
#pragma unroll
    for (int e = 0; e < 8; ++e) {
      const float p = acc[e] * inv;
      scores_out[(size_t)tok * NEXP + e] = p;
      if (acc[e] > bv) { bv = acc[e]; best = e; }
    }
    expert[tok] = best;
    atomicAdd(&counts[best], 1);
  }
}

__global__ void offsets_kernel(const int* __restrict__ counts, int* __restrict__ offs)
{
  if (threadIdx.x == 0 && blockIdx.x == 0) {
    int a = 0;
    for (int e = 0; e < NEXP; ++e) { offs[e] = a; a += counts[e]; }
    offs[NEXP] = a;
  }
}

__global__ __launch_bounds__(256) void scatter_kernel(
    const int* __restrict__ expert, const int* __restrict__ offs,
    int* __restrict__ cursor, int* __restrict__ perm)
{
  const int t = blockIdx.x * 256 + threadIdx.x;
  if (t >= TOKS) return;
  const int e = expert[t];
  const int pos = atomicAdd(&cursor[e], 1);
  perm[offs[e] + pos] = t;
}

extern "C" void kernel_launch(void* const* d_in, const int* in_sizes, int n_in,
                              void* d_out, int out_size, void* d_ws, size_t ws_size,
                              hipStream_t stream) {
  const float* hidden = (const float*)d_in[0];
  const float* Wq  = (const float*)d_in[1];
  const float* bq  = (const float*)d_in[2];
  const float* Wk  = (const float*)d_in[3];
  const float* bk  = (const float*)d_in[4];
  const float* Wv  = (const float*)d_in[5];
  const float* bv  = (const float*)d_in[6];
  const float* Wao = (const float*)d_in[7];
  const float* bao = (const float*)d_in[8];
  const float* ln1g = (const float*)d_in[9];
  const float* ln1b = (const float*)d_in[10];
  const float* Wr  = (const float*)d_in[11];
  const float* br  = (const float*)d_in[12];
  const float* Wi  = (const float*)d_in[13];
  const float* bi  = (const float*)d_in[14];
  const float* Wo  = (const float*)d_in[15];
  const float* bo  = (const float*)d_in[16];
  const float* ln2g = (const float*)d_in[17];
  const float* ln2b = (const float*)d_in[18];

  float* out = (float*)d_out;
  float* scores_out = out + (size_t)TOKS * HDIM;

  const size_t M1 = (size_t)TOKS * HDIM;     // 6.29M floats
  const size_t HW = (size_t)HDIM * HDIM;     // 589824
  float* ws = (float*)d_ws;
  // ---- arena (by liveness) ----
  // phase A/B: QKVb fused [8192][2304] at [0,3M1); ctxb [3M1,4M1)
  float* QKVb = ws;
  float* ctxb = ws + 3 * M1;
  float* bqkv = ws + 3 * M1;                 // first 2304 floats of ctxb region; dead before attention writes ctxb
  // split operands (phase A: hidden; phase C: ctx — same buffers)
  short* Hh = (short*)(ws + 4 * M1);         // M1 shorts
  short* Hl = Hh + M1;                       // ends at 5M1 floats
  short* Ch = Hh; short* Cl = Hl;
  // transposed split weights at [5M1, 5M1+2.36M floats)
  short* wt = (short*)(ws + 5 * M1);
  short* WqkvhT = wt;                        // [2304][768]
  short* WqkvlT = wt + 3 * HW;
  short* WaohT  = wt + 6 * HW;
  short* WaolT  = wt + 7 * HW;
  // phase C/D/E
  float* aoproj   = ws;                      // reuse QKVb (dead after attention)
  float* attn_out = ws + M1;
  float* tmp2     = ws;
  short* Abf    = (short*)(ws + 2 * M1);     // phase E (identical to R3 layout)
  short* WiT    = Abf + M1;
  short* WoT    = WiT + (size_t)NEXP * FDIM * HDIM;
  short* interb = WoT + (size_t)HDIM * FDIM;
  int* ints   = (int*)(interb + (size_t)TOKS * FDIM);
  int* perm   = ints;
  int* expert = ints + TOKS;
  int* counts = expert + TOKS;
  int* offs   = counts + NEXP;
  int* cursor = offs + NEXP + 1;

  hipMemsetAsync(counts, 0, (NEXP + NEXP + 1 + NEXP) * sizeof(int), stream);
  hipMemcpyAsync(bqkv,        bq, HDIM * sizeof(float), hipMemcpyDeviceToDevice, stream);
  hipMemcpyAsync(bqkv + 768,  bk, HDIM * sizeof(float), hipMemcpyDeviceToDevice, stream);
  hipMemcpyAsync(bqkv + 1536, bv, HDIM * sizeof(float), hipMemcpyDeviceToDevice, stream);

  const dim3 blk(256);
  // --- split prep ---
  convert_split<<<dim3(TOKS * HDIM / 4 / 256), blk, 0, stream>>>(hidden, Hh, Hl, TOKS * HDIM / 4);
  transpose_split<<<dim3(24, 24), blk, 0, stream>>>(Wq,  WqkvhT,          WqkvlT,          HDIM, HDIM);
  transpose_split<<<dim3(24, 24), blk, 0, stream>>>(Wk,  WqkvhT + HW,     WqkvlT + HW,     HDIM, HDIM);
  transpose_split<<<dim3(24, 24), blk, 0, stream>>>(Wv,  WqkvhT + 2 * HW, WqkvlT + 2 * HW, HDIM, HDIM);
  transpose_split<<<dim3(24, 24), blk, 0, stream>>>(Wao, WaohT,           WaolT,           HDIM, HDIM);

  // --- fused QKV projection (split-bf16 MFMA) ---
  gemm_split_mfma<<<dim3(QKVSTR / 128, TOKS / 128), blk, 0, stream>>>(
      Hh, Hl, WqkvhT, WqkvlT, bqkv, QKVb, QKVSTR, HDIM);

  attention_kernel<<<dim3(SEQ / 64, NHEAD, BATCH), blk, 0, stream>>>(QKVb, ctxb);

  // --- AO projection (split-bf16 MFMA) + LN1 ---
  convert_split<<<dim3(TOKS * HDIM / 4 / 256), blk, 0, stream>>>(ctxb, Ch, Cl, TOKS * HDIM / 4);
  gemm_split_mfma<<<dim3(HDIM / 128, TOKS / 128), blk, 0, stream>>>(
      Ch, Cl, WaohT, WaolT, bao, aoproj, HDIM, HDIM);
  add_ln_kernel<<<dim3(TOKS), blk, 0, stream>>>(aoproj, hidden, ln1g, ln1b, attn_out);

  // --- router + dispatch ---
  router_kernel<<<dim3(TOKS / 4), blk, 0, stream>>>(attn_out, Wr, br, scores_out, expert, counts);
  offsets_kernel<<<dim3(1), dim3(64), 0, stream>>>(counts, offs);
  scatter_kernel<<<dim3(TOKS / 256), blk, 0, stream>>>(expert, offs, cursor, perm);

  // --- expert FFN (bf16 MFMA, unchanged) ---
  transpose_to_bf16<<<dim3(FDIM / 32, HDIM / 32, NEXP), blk, 0, stream>>>(Wi, WiT, HDIM, FDIM);
  transpose_to_bf16<<<dim3(HDIM / 32, FDIM / 32, 1), blk, 0, stream>>>(Wo, WoT, FDIM, HDIM);
  convert_bf16<<<dim3(TOKS * HDIM / 4 / 256), blk, 0, stream>>>(attn_out, Abf, TOKS * HDIM / 4);

  expert_up_mfma<<<dim3(TOKS / 128, FDIM / 128, NEXP), blk, 0, stream>>>(
      Abf, WiT, bi, perm, offs, interb);
  wo_mfma<<<dim3(HDIM / 128, TOKS / 128), blk, 0, stream>>>(interb, WoT, bo, tmp2);
  add_ln_kernel<<<dim3(TOKS), blk, 0, stream>>>(tmp2, attn_out, ln2g, ln2b, out);
}

// Round 6
// 1189.207 us; speedup vs baseline: 2.1987x; 1.1413x over previous
//
#include <hip/hip_runtime.h>
#include <math.h>
#include <stdint.h>

#define TOKS 8192
#define HDIM 768
#define FDIM 3072
#define NEXP 8
#define NHEAD 12
#define SEQ 1024
#define BATCH 8

typedef __attribute__((ext_vector_type(8))) short s16x8;   // 8 bf16 = 4 VGPR
typedef __attribute__((ext_vector_type(4))) short s16x4;
typedef __attribute__((ext_vector_type(4))) float f32x4;

__device__ __forceinline__ short f2bf(float f) {
  uint32_t u = __float_as_uint(f);
  uint32_t r = (u + 0x7fffu + ((u >> 16) & 1u)) >> 16;   // RTN-even
  return (short)(r & 0xffffu);
}
__device__ __forceinline__ float bf2f(short h) {
  return __uint_as_float(((uint32_t)(uint16_t)h) << 16);
}
__device__ __forceinline__ void gload16(const void* g, void* l) {
  __builtin_amdgcn_global_load_lds(
      (const __attribute__((address_space(1))) uint32_t*)g,
      (__attribute__((address_space(3))) uint32_t*)l, 16, 0, 0);
}

// ============ f32 -> (hi,lo) bf16 split, 4 elems/thread ============
__global__ __launch_bounds__(256) void convert_split(
    const float* __restrict__ X, short* __restrict__ Xh, short* __restrict__ Xl, int n4)
{
  const int i = blockIdx.x * 256 + threadIdx.x;
  if (i >= n4) return;
  const float4 v = ((const float4*)X)[i];
  const float a[4] = {v.x, v.y, v.z, v.w};
  s16x4 h, l;
#pragma unroll
  for (int j = 0; j < 4; ++j) {
    h[j] = f2bf(a[j]);
    l[j] = f2bf(a[j] - bf2f(h[j]));
  }
  ((s16x4*)Xh)[i] = h;
  ((s16x4*)Xl)[i] = l;
}

// ============ transpose + split: WT{h,l}[n][k] = split(W[k][n]) ============
__global__ __launch_bounds__(256) void transpose_split(
    const float* __restrict__ W, short* __restrict__ WTh, short* __restrict__ WTl,
    int K, int N)
{
  __shared__ float t[32][33];
  const int tid = threadIdx.x;
  const int tx = tid & 31, ty = tid >> 5;
  const int n0 = blockIdx.x * 32, k0 = blockIdx.y * 32;
#pragma unroll
  for (int r = 0; r < 4; ++r)
    t[ty + r * 8][tx] = W[(size_t)(k0 + ty + r * 8) * N + n0 + tx];
  __syncthreads();
#pragma unroll
  for (int r = 0; r < 4; ++r) {
    const float v = t[tx][ty + r * 8];
    const short h = f2bf(v);
    WTh[(size_t)(n0 + ty + r * 8) * K + k0 + tx] = h;
    WTl[(size_t)(n0 + ty + r * 8) * K + k0 + tx] = f2bf(v - bf2f(h));
  }
}

// ============ split-bf16 MFMA GEMM (f32 out): C = (Ah+Al)@(Bh+Bl)^T + bias ============
__global__ __launch_bounds__(256) void gemm_split_mfma(
    const short* __restrict__ Ah, const short* __restrict__ Al,
    const short* __restrict__ BhT, const short* __restrict__ BlT,
    const float* __restrict__ bias, float* __restrict__ C,
    int N, int K)
{
  __shared__ __align__(16) short lAh[8 * 512];
  __shared__ __align__(16) short lAl[8 * 512];
  __shared__ __align__(16) short lBh[8 * 512];
  __shared__ __align__(16) short lBl[8 * 512];
  const int tid = threadIdx.x;
  const int w = tid >> 6, lane = tid & 63;
  const int wr = w >> 1, wc = w & 1;
  const int row0 = blockIdx.y * 128, col0 = blockIdx.x * 128;
  const int sr = lane & 15, kg = lane >> 4;
  const size_t a0 = (size_t)(row0 + 2 * w * 16 + sr) * K + kg * 8;
  const size_t a1 = a0 + (size_t)16 * K;
  const size_t b0 = (size_t)(col0 + 2 * w * 16 + sr) * K + kg * 8;
  const size_t b1 = b0 + (size_t)16 * K;
  short* dAh0 = &lAh[(2 * w) * 512]; short* dAh1 = dAh0 + 512;
  short* dAl0 = &lAl[(2 * w) * 512]; short* dAl1 = dAl0 + 512;
  short* dBh0 = &lBh[(2 * w) * 512]; short* dBh1 = dBh0 + 512;
  short* dBl0 = &lBl[(2 * w) * 512]; short* dBl1 = dBl0 + 512;
  f32x4 acc[4][4] = {};
  for (int k0 = 0; k0 < K; k0 += 32) {
    gload16(Ah + a0 + k0, dAh0);
    gload16(Ah + a1 + k0, dAh1);
    gload16(Al + a0 + k0, dAl0);
    gload16(Al + a1 + k0, dAl1);
    gload16(BhT + b0 + k0, dBh0);
    gload16(BhT + b1 + k0, dBh1);
    gload16(BlT + b0 + k0, dBl0);
    gload16(BlT + b1 + k0, dBl1);
    __syncthreads();
    s16x8 ah[4], al[4], bh[4], bl[4];
#pragma unroll
    for (int i = 0; i < 4; ++i) {
      ah[i] = *(const s16x8*)&lAh[(wr * 4 + i) * 512 + lane * 8];
      al[i] = *(const s16x8*)&lAl[(wr * 4 + i) * 512 + lane * 8];
      bh[i] = *(const s16x8*)&lBh[(wc * 4 + i) * 512 + lane * 8];
      bl[i] = *(const s16x8*)&lBl[(wc * 4 + i) * 512 + lane * 8];
    }
#pragma unroll
    for (int mi = 0; mi < 4; ++mi)
#pragma unroll
      for (int ni = 0; ni < 4; ++ni) {
        acc[mi][ni] = __builtin_amdgcn_mfma_f32_16x16x32_bf16(ah[mi], bh[ni], acc[mi][ni], 0, 0, 0);
        acc[mi][ni] = __builtin_amdgcn_mfma_f32_16x16x32_bf16(ah[mi], bl[ni], acc[mi][ni], 0, 0, 0);
        acc[mi][ni] = __builtin_amdgcn_mfma_f32_16x16x32_bf16(al[mi], bh[ni], acc[mi][ni], 0, 0, 0);
      }
    __syncthreads();
  }
  const int cl = lane & 15, rg = lane >> 4;
#pragma unroll
  for (int mi = 0; mi < 4; ++mi)
#pragma unroll
    for (int r = 0; r < 4; ++r) {
      const int row = row0 + wr * 64 + mi * 16 + rg * 4 + r;
#pragma unroll
      for (int ni = 0; ni < 4; ++ni) {
        const int c = col0 + wc * 64 + ni * 16 + cl;
        C[(size_t)row * N + c] = acc[mi][ni][r] + bias[c];
      }
    }
}

// ============ QKV split-GEMM: writes split-bf16 Q,K (strided 1536) + transposed split V ============
// A [8192][768] split, BT [2304][768] split (Wq|Wk|Wv rows). N=2304, K=768.
__global__ __launch_bounds__(256) void qkv_split_mfma(
    const short* __restrict__ Ah, const short* __restrict__ Al,
    const short* __restrict__ BhT, const short* __restrict__ BlT,
    const float* __restrict__ bias,
    short* __restrict__ QKh, short* __restrict__ QKl,
    short* __restrict__ VTh, short* __restrict__ VTl)
{
  const int K = 768;
  __shared__ __align__(16) short lAh[8 * 512];
  __shared__ __align__(16) short lAl[8 * 512];
  __shared__ __align__(16) short lBh[8 * 512];
  __shared__ __align__(16) short lBl[8 * 512];
  const int tid = threadIdx.x;
  const int w = tid >> 6, lane = tid & 63;
  const int wr = w >> 1, wc = w & 1;
  const int row0 = blockIdx.y * 128, col0 = blockIdx.x * 128;
  const int sr = lane & 15, kg = lane >> 4;
  const size_t a0 = (size_t)(row0 + 2 * w * 16 + sr) * K + kg * 8;
  const size_t a1 = a0 + (size_t)16 * K;
  const size_t b0 = (size_t)(col0 + 2 * w * 16 + sr) * K + kg * 8;
  const size_t b1 = b0 + (size_t)16 * K;
  short* dAh0 = &lAh[(2 * w) * 512]; short* dAh1 = dAh0 + 512;
  short* dAl0 = &lAl[(2 * w) * 512]; short* dAl1 = dAl0 + 512;
  short* dBh0 = &lBh[(2 * w) * 512]; short* dBh1 = dBh0 + 512;
  short* dBl0 = &lBl[(2 * w) * 512]; short* dBl1 = dBl0 + 512;
  f32x4 acc[4][4] = {};
  for (int k0 = 0; k0 < K; k0 += 32) {
    gload16(Ah + a0 + k0, dAh0);
    gload16(Ah + a1 + k0, dAh1);
    gload16(Al + a0 + k0, dAl0);
    gload16(Al + a1 + k0, dAl1);
    gload16(BhT + b0 + k0, dBh0);
    gload16(BhT + b1 + k0, dBh1);
    gload16(BlT + b0 + k0, dBl0);
    gload16(BlT + b1 + k0, dBl1);
    __syncthreads();
    s16x8 ah[4], al[4], bh[4], bl[4];
#pragma unroll
    for (int i = 0; i < 4; ++i) {
      ah[i] = *(const s16x8*)&lAh[(wr * 4 + i) * 512 + lane * 8];
      al[i] = *(const s16x8*)&lAl[(wr * 4 + i) * 512 + lane * 8];
      bh[i] = *(const s16x8*)&lBh[(wc * 4 + i) * 512 + lane * 8];
      bl[i] = *(const s16x8*)&lBl[(wc * 4 + i) * 512 + lane * 8];
    }
#pragma unroll
    for (int mi = 0; mi < 4; ++mi)
#pragma unroll
      for (int ni = 0; ni < 4; ++ni) {
        acc[mi][ni] = __builtin_amdgcn_mfma_f32_16x16x32_bf16(ah[mi], bh[ni], acc[mi][ni], 0, 0, 0);
        acc[mi][ni] = __builtin_amdgcn_mfma_f32_16x16x32_bf16(ah[mi], bl[ni], acc[mi][ni], 0, 0, 0);
        acc[mi][ni] = __builtin_amdgcn_mfma_f32_16x16x32_bf16(al[mi], bh[ni], acc[mi][ni], 0, 0, 0);
      }
    __syncthreads();
  }
  const int cl = lane & 15, rg = lane >> 4;
#pragma unroll
  for (int mi = 0; mi < 4; ++mi)
#pragma unroll
    for (int ni = 0; ni < 4; ++ni) {
      const int c = col0 + wc * 64 + ni * 16 + cl;
      const int rowb = row0 + wr * 64 + mi * 16 + rg * 4;
      s16x4 hv, lv;
#pragma unroll
      for (int r = 0; r < 4; ++r) {
        const float v = acc[mi][ni][r] + bias[c];
        const short hh = f2bf(v);
        hv[r] = hh;
        lv[r] = f2bf(v - bf2f(hh));
      }
      if (c < 1536) {   // Q or K column: row-major strided store
#pragma unroll
        for (int r = 0; r < 4; ++r) {
          QKh[(size_t)(rowb + r) * 1536 + c] = hv[r];
          QKl[(size_t)(rowb + r) * 1536 + c] = lv[r];
        }
      } else {          // V column: transposed store VT[b][h][d][s]
        const int dall = c - 1536;
        const size_t vi = (((size_t)((rowb >> 10) * NHEAD + (dall >> 6))) * 64 + (dall & 63)) * 1024
                          + (rowb & 1023);
        *(s16x4*)(VTh + vi) = hv;
        *(s16x4*)(VTl + vi) = lv;
      }
    }
}

// ============ MFMA flash attention, split-bf16 (3-product) QK^T and PV ============
// QK{h,l} [8192][1536] (Q cols 0..767, K cols 768..1535), VT{h,l} [B*NH][64][1024].
// Block: 128 q-rows, 4 waves (2x2: wr=q-half, wc=k/d-half), KVBLK=64.
__global__ __launch_bounds__(256) void attention_mfma(
    const short* __restrict__ QKh, const short* __restrict__ QKl,
    const short* __restrict__ VTh, const short* __restrict__ VTl,
    float* __restrict__ ctx)
{
  __shared__ __align__(16) short lPh[16 * 512];   // P hi, fragment-ordered [mb][ks]
  __shared__ __align__(16) short lPl[16 * 512];   // P lo
  __shared__ float redm[2][128];
  __shared__ float reds[2][128];
  const int tid = threadIdx.x;
  const int w = tid >> 6, lane = tid & 63;
  const int wr = w >> 1, wc = w & 1;
  const int b = blockIdx.z, h = blockIdx.y;
  const int q0 = blockIdx.x * 128;
  const int sr = lane & 15, kg = lane >> 4;   // frag-load mapping
  const int cl = sr, rg = kg;                 // C-layout mapping (same bits)

  // Q fragments held in registers for the whole block
  s16x8 qh[4][2], ql[4][2];
  {
    const size_t qbase = ((size_t)b * SEQ + q0 + wr * 64 + sr) * 1536 + h * 64 + kg * 8;
#pragma unroll
    for (int mi = 0; mi < 4; ++mi)
#pragma unroll
      for (int ks = 0; ks < 2; ++ks) {
        const size_t o = qbase + (size_t)mi * (16 * 1536) + ks * 32;
        qh[mi][ks] = *(const s16x8*)(QKh + o);
        ql[mi][ks] = *(const s16x8*)(QKl + o);
      }
  }
  float m_run[4][4], l_run[4][4];
#pragma unroll
  for (int mi = 0; mi < 4; ++mi)
#pragma unroll
    for (int r = 0; r < 4; ++r) { m_run[mi][r] = -3.0e38f; l_run[mi][r] = 0.f; }
  f32x4 acc_o[4][2] = {};

  for (int kt = 0; kt < SEQ; kt += 64) {
    // --- K fragments (direct global, per-lane 16B) ---
    s16x8 kh[2][2], kl2[2][2];
    {
      const size_t kbase = ((size_t)b * SEQ + kt + wc * 32 + sr) * 1536 + 768 + h * 64 + kg * 8;
#pragma unroll
      for (int ni = 0; ni < 2; ++ni)
#pragma unroll
        for (int ks = 0; ks < 2; ++ks) {
          const size_t o = kbase + (size_t)ni * (16 * 1536) + ks * 32;
          kh[ni][ks] = *(const s16x8*)(QKh + o);
          kl2[ni][ks] = *(const s16x8*)(QKl + o);
        }
    }
    // --- S = (Qh+Ql)(Kh+Kl)^T, 3 products ---
    f32x4 accs[4][2] = {};
#pragma unroll
    for (int ks = 0; ks < 2; ++ks)
#pragma unroll
      for (int ni = 0; ni < 2; ++ni)
#pragma unroll
        for (int mi = 0; mi < 4; ++mi) {
          accs[mi][ni] = __builtin_amdgcn_mfma_f32_16x16x32_bf16(qh[mi][ks], kh[ni][ks], accs[mi][ni], 0, 0, 0);
          accs[mi][ni] = __builtin_amdgcn_mfma_f32_16x16x32_bf16(qh[mi][ks], kl2[ni][ks], accs[mi][ni], 0, 0, 0);
          accs[mi][ni] = __builtin_amdgcn_mfma_f32_16x16x32_bf16(ql[mi][ks], kh[ni][ks], accs[mi][ni], 0, 0, 0);
        }
    // --- V fragments: issue now, consumed after softmax (latency hidden) ---
    s16x8 vh[2][2], vl2[2][2];
    {
      const size_t vbase = (((size_t)(b * NHEAD + h)) * 64 + wc * 32 + sr) * 1024 + kt + kg * 8;
#pragma unroll
      for (int ni = 0; ni < 2; ++ni)
#pragma unroll
        for (int ks = 0; ks < 2; ++ks) {
          const size_t o = vbase + (size_t)ni * (16 * 1024) + ks * 32;
          vh[ni][ks] = *(const s16x8*)(VTh + o);
          vl2[ni][ks] = *(const s16x8*)(VTl + o);
        }
    }
    // --- scale 1/8 (exact) ---
#pragma unroll
    for (int mi = 0; mi < 4; ++mi)
#pragma unroll
      for (int ni = 0; ni < 2; ++ni)
#pragma unroll
        for (int r = 0; r < 4; ++r)
          accs[mi][ni][r] *= 0.125f;
    // --- partial row max (ni pair + 16-lane cl butterfly) ---
    float mx[4][4];
#pragma unroll
    for (int mi = 0; mi < 4; ++mi)
#pragma unroll
      for (int r = 0; r < 4; ++r) {
        float v = fmaxf(accs[mi][0][r], accs[mi][1][r]);
        v = fmaxf(v, __shfl_xor(v, 1));
        v = fmaxf(v, __shfl_xor(v, 2));
        v = fmaxf(v, __shfl_xor(v, 4));
        v = fmaxf(v, __shfl_xor(v, 8));
        mx[mi][r] = v;
      }
    if (cl == 0) {
#pragma unroll
      for (int mi = 0; mi < 4; ++mi)
#pragma unroll
        for (int r = 0; r < 4; ++r)
          redm[wc][wr * 64 + mi * 16 + rg * 4 + r] = mx[mi][r];
    }
    __syncthreads();
    // --- combine max across wc, rescale O and l ---
#pragma unroll
    for (int mi = 0; mi < 4; ++mi)
#pragma unroll
      for (int r = 0; r < 4; ++r) {
        const int row = wr * 64 + mi * 16 + rg * 4 + r;
        const float tm = fmaxf(redm[0][row], redm[1][row]);
        const float mn = fmaxf(m_run[mi][r], tm);
        const float c = __expf(m_run[mi][r] - mn);
        m_run[mi][r] = mn;
        l_run[mi][r] *= c;
        acc_o[mi][0][r] *= c;
        acc_o[mi][1][r] *= c;
      }
    // --- P = exp(s-m): split-bf16 to LDS (fragment order) + partial row sums ---
    float psum[4][4];
#pragma unroll
    for (int mi = 0; mi < 4; ++mi)
#pragma unroll
      for (int r = 0; r < 4; ++r) {
        const int sbase = ((wr * 4 + mi) * 2 + wc) * 512 + (rg * 4 + r) * 8 + (cl & 7);
        const float s0 = __expf(accs[mi][0][r] - m_run[mi][r]);
        const float s1 = __expf(accs[mi][1][r] - m_run[mi][r]);
        {
          const short h0 = f2bf(s0);
          const int idx = sbase + (cl >> 3) * 128;          // ni=0 -> kg 0..1
          lPh[idx] = h0;
          lPl[idx] = f2bf(s0 - bf2f(h0));
        }
        {
          const short h1 = f2bf(s1);
          const int idx = sbase + (2 + (cl >> 3)) * 128;    // ni=1 -> kg 2..3
          lPh[idx] = h1;
          lPl[idx] = f2bf(s1 - bf2f(h1));
        }
        float v = s0 + s1;
        v += __shfl_xor(v, 1);
        v += __shfl_xor(v, 2);
        v += __shfl_xor(v, 4);
        v += __shfl_xor(v, 8);
        psum[mi][r] = v;
      }
    if (cl == 0) {
#pragma unroll
      for (int mi = 0; mi < 4; ++mi)
#pragma unroll
        for (int r = 0; r < 4; ++r)
          reds[wc][wr * 64 + mi * 16 + rg * 4 + r] = psum[mi][r];
    }
    __syncthreads();
#pragma unroll
    for (int mi = 0; mi < 4; ++mi)
#pragma unroll
      for (int r = 0; r < 4; ++r) {
        const int row = wr * 64 + mi * 16 + rg * 4 + r;
        l_run[mi][r] += reds[0][row] + reds[1][row];
      }
    // --- O += (Ph+Pl)(Vh+Vl), 3 products ---
#pragma unroll
    for (int ks = 0; ks < 2; ++ks) {
      s16x8 pf[4], pg[4];
#pragma unroll
      for (int mi = 0; mi < 4; ++mi) {
        pf[mi] = *(const s16x8*)&lPh[((wr * 4 + mi) * 2 + ks) * 512 + lane * 8];
        pg[mi] = *(const s16x8*)&lPl[((wr * 4 + mi) * 2 + ks) * 512 + lane * 8];
      }
#pragma unroll
      for (int ni = 0; ni < 2; ++ni)
#pragma unroll
        for (int mi = 0; mi < 4; ++mi) {
          acc_o[mi][ni] = __builtin_amdgcn_mfma_f32_16x16x32_bf16(pf[mi], vh[ni][ks], acc_o[mi][ni], 0, 0, 0);
          acc_o[mi][ni] = __builtin_amdgcn_mfma_f32_16x16x32_bf16(pf[mi], vl2[ni][ks], acc_o[mi][ni], 0, 0, 0);
          acc_o[mi][ni] = __builtin_amdgcn_mfma_f32_16x16x32_bf16(pg[mi], vh[ni][ks], acc_o[mi][ni], 0, 0, 0);
        }
    }
    __syncthreads();   // lP/red consumed before next tile overwrites
  }
  // --- epilogue: ctx[b, q, h*64+d] = O / l ---
#pragma unroll
  for (int mi = 0; mi < 4; ++mi)
#pragma unroll
    for (int ni = 0; ni < 2; ++ni)
#pragma unroll
      for (int r = 0; r < 4; ++r) {
        const int row = q0 + wr * 64 + mi * 16 + rg * 4 + r;
        const int d = h * 64 + wc * 32 + ni * 16 + cl;
        ctx[((size_t)b * SEQ + row) * HDIM + d] = acc_o[mi][ni][r] / l_run[mi][r];
      }
}

// ============ f32->bf16 elementwise (expert path A) ============
__global__ __launch_bounds__(256) void convert_bf16(
    const float* __restrict__ X, short* __restrict__ Y, int n4)
{
  const int i = blockIdx.x * 256 + threadIdx.x;
  if (i >= n4) return;
  const float4 v = ((const float4*)X)[i];
  s16x4 s;
  s[0] = f2bf(v.x); s[1] = f2bf(v.y); s[2] = f2bf(v.z); s[3] = f2bf(v.w);
  ((s16x4*)Y)[i] = s;
}

// ============ transpose + f32->bf16 (expert weights) ============
__global__ __launch_bounds__(256) void transpose_to_bf16(
    const float* __restrict__ W, short* __restrict__ WT, int K, int N)
{
  const size_t off = (size_t)blockIdx.z * (size_t)K * N;
  const float* Wp = W + off;
  short* WTp = WT + off;
  __shared__ float t[32][33];
  const int tid = threadIdx.x;
  const int tx = tid & 31, ty = tid >> 5;
  const int n0 = blockIdx.x * 32, k0 = blockIdx.y * 32;
#pragma unroll
  for (int r = 0; r < 4; ++r)
    t[ty + r * 8][tx] = Wp[(size_t)(k0 + ty + r * 8) * N + n0 + tx];
  __syncthreads();
#pragma unroll
  for (int r = 0; r < 4; ++r)
    WTp[(size_t)(n0 + ty + r * 8) * K + k0 + tx] = f2bf(t[tx][ty + r * 8]);
}

// ============ MFMA expert up-proj ============
__global__ __launch_bounds__(256) void expert_up_mfma(
    const short* __restrict__ Abf, const short* __restrict__ WiT,
    const float* __restrict__ bi, const int* __restrict__ perm,
    const int* __restrict__ offs, short* __restrict__ interb)
{
  const int e = blockIdx.z;
  const int seg_start = offs[e], seg_end = offs[e + 1];
  const int row0 = seg_start + blockIdx.x * 128;
  if (row0 >= seg_end) return;
  __shared__ __align__(16) short lA[8 * 512];
  __shared__ __align__(16) short lB[8 * 512];
  __shared__ int toks[128];
  const int tid = threadIdx.x;
  const int w = tid >> 6, lane = tid & 63;
  const int wr = w >> 1, wc = w & 1;
  const int col0 = blockIdx.y * 128;
  if (tid < 128) {
    const int rr = row0 + tid;
    toks[tid] = (rr < seg_end) ? perm[rr] : -1;
  }
  __syncthreads();
  const int sr = lane & 15, kg = lane >> 4;
  int t0 = toks[2 * w * 16 + sr];        if (t0 < 0) t0 = toks[0];
  int t1 = toks[(2 * w + 1) * 16 + sr];  if (t1 < 0) t1 = toks[0];
  const short* pa0 = Abf + (size_t)t0 * HDIM + kg * 8;
  const short* pa1 = Abf + (size_t)t1 * HDIM + kg * 8;
  const short* Bt = WiT + (size_t)e * FDIM * HDIM;
  const short* pb0 = Bt + (size_t)(col0 + 2 * w * 16 + sr) * HDIM + kg * 8;
  const short* pb1 = pb0 + (size_t)16 * HDIM;
  short* dA0 = &lA[(2 * w) * 512];
  short* dA1 = &lA[(2 * w + 1) * 512];
  short* dB0 = &lB[(2 * w) * 512];
  short* dB1 = &lB[(2 * w + 1) * 512];
  f32x4 acc[4][4] = {};
  for (int k0 = 0; k0 < HDIM; k0 += 32) {
    gload16(pa0 + k0, dA0);
    gload16(pa1 + k0, dA1);
    gload16(pb0 + k0, dB0);
    gload16(pb1 + k0, dB1);
    __syncthreads();
    s16x8 af[4], bg[4];
#pragma unroll
    for (int i = 0; i < 4; ++i) {
      af[i] = *(const s16x8*)&lA[(wr * 4 + i) * 512 + lane * 8];
      bg[i] = *(const s16x8*)&lB[(wc * 4 + i) * 512 + lane * 8];
    }
#pragma unroll
    for (int mi = 0; mi < 4; ++mi)
#pragma unroll
      for (int ni = 0; ni < 4; ++ni)
        acc[mi][ni] = __builtin_amdgcn_mfma_f32_16x16x32_bf16(af[mi], bg[ni], acc[mi][ni], 0, 0, 0);
    __syncthreads();
  }
  const int cl = lane & 15, rg = lane >> 4;
#pragma unroll
  for (int mi = 0; mi < 4; ++mi) {
#pragma unroll
    for (int r = 0; r < 4; ++r) {
      const int rl = wr * 64 + mi * 16 + rg * 4 + r;
      const int tok = toks[rl];
      if (tok < 0) continue;
#pragma unroll
      for (int ni = 0; ni < 4; ++ni) {
        const int c = col0 + wc * 64 + ni * 16 + cl;
        float v = acc[mi][ni][r] + bi[(size_t)e * FDIM + c];
        v = 0.5f * v * (1.0f + erff(v * 0.70710678118654752f));
        interb[(size_t)tok * FDIM + c] = f2bf(v);
      }
    }
  }
}

// ============ MFMA down-proj ============
__global__ __launch_bounds__(256) void wo_mfma(
    const short* __restrict__ Ab, const short* __restrict__ BT,
    const float* __restrict__ bias, float* __restrict__ C)
{
  __shared__ __align__(16) short lA[8 * 512];
  __shared__ __align__(16) short lB[8 * 512];
  const int tid = threadIdx.x;
  const int w = tid >> 6, lane = tid & 63;
  const int wr = w >> 1, wc = w & 1;
  const int row0 = blockIdx.y * 128, col0 = blockIdx.x * 128;
  const int sr = lane & 15, kg = lane >> 4;
  const short* pa0 = Ab + (size_t)(row0 + 2 * w * 16 + sr) * FDIM + kg * 8;
  const short* pa1 = pa0 + (size_t)16 * FDIM;
  const short* pb0 = BT + (size_t)(col0 + 2 * w * 16 + sr) * FDIM + kg * 8;
  const short* pb1 = pb0 + (size_t)16 * FDIM;
  short* dA0 = &lA[(2 * w) * 512];
  short* dA1 = &lA[(2 * w + 1) * 512];
  short* dB0 = &lB[(2 * w) * 512];
  short* dB1 = &lB[(2 * w + 1) * 512];
  f32x4 acc[4][4] = {};
  for (int k0 = 0; k0 < FDIM; k0 += 32) {
    gload16(pa0 + k0, dA0);
    gload16(pa1 + k0, dA1);
    gload16(pb0 + k0, dB0);
    gload16(pb1 + k0, dB1);
    __syncthreads();
    s16x8 af[4], bg[4];
#pragma unroll
    for (int i = 0; i < 4; ++i) {
      af[i] = *(const s16x8*)&lA[(wr * 4 + i) * 512 + lane * 8];
      bg[i] = *(const s16x8*)&lB[(wc * 4 + i) * 512 + lane * 8];
    }
#pragma unroll
    for (int mi = 0; mi < 4; ++mi)
#pragma unroll
      for (int ni = 0; ni < 4; ++ni)
        acc[mi][ni] = __builtin_amdgcn_mfma_f32_16x16x32_bf16(af[mi], bg[ni], acc[mi][ni], 0, 0, 0);
    __syncthreads();
  }
  const int cl = lane & 15, rg = lane >> 4;
#pragma unroll
  for (int mi = 0; mi < 4; ++mi) {
#pragma unroll
    for (int r = 0; r < 4; ++r) {
      const int row = row0 + wr * 64 + mi * 16 + rg * 4 + r;
#pragma unroll
      for (int ni = 0; ni < 4; ++ni) {
        const int c = col0 + wc * 64 + ni * 16 + cl;
        C[(size_t)row * HDIM + c] = acc[mi][ni][r] + bias[c];
      }
    }
  }
}

// ============ residual add + LayerNorm ============
__global__ __launch_bounds__(256) void add_ln_kernel(
    const float* __restrict__ X, const float* __restrict__ R,
    const float* __restrict__ g, const float* __restrict__ bb,
    float* __restrict__ out)
{
  const int t = blockIdx.x;
  const int tid = threadIdx.x;
  const float* x = X + (size_t)t * HDIM;
  const float* r = R + (size_t)t * HDIM;
  float v[3];
  float sum = 0.f, ssq = 0.f;
#pragma unroll
  for (int i = 0; i < 3; ++i) {
    const float val = x[tid + i * 256] + r[tid + i * 256];
    v[i] = val;
    sum += val;
    ssq += val * val;
  }
#pragma unroll
  for (int o = 32; o > 0; o >>= 1) {
    sum += __shfl_down(sum, o);
    ssq += __shfl_down(ssq, o);
  }
  __shared__ float red[10];
  const int wid = tid >> 6, lane = tid & 63;
  if (lane == 0) { red[wid] = sum; red[4 + wid] = ssq; }
  __syncthreads();
  if (tid == 0) {
    const float s = red[0] + red[1] + red[2] + red[3];
    const float q = red[4] + red[5] + red[6] + red[7];
    const float mean = s * (1.f / HDIM);
    const float var = q * (1.f / HDIM) - mean * mean;
    red[8] = mean;
    red[9] = rsqrtf(fmaxf(var, 0.f) + 1e-12f);
  }
  __syncthreads();
  const float mean = red[8], rstd = red[9];
#pragma unroll
  for (int i = 0; i < 3; ++i) {
    const int idx = tid + i * 256;
    out[(size_t)t * HDIM + idx] = g[idx] * (v[i] - mean) * rstd + bb[idx];
  }
}

// ============ router (f32 — keeps argmax path bit-identical) ============
__global__ __launch_bounds__(256) void router_kernel(
    const float* __restrict__ X, const float* __restrict__ Wr,
    const float* __restrict__ br, float* __restrict__ scores_out,
    int* __restrict__ expert, int* __restrict__ counts)
{
  const int wid = threadIdx.x >> 6, lane = threadIdx.x & 63;
  const int tok = blockIdx.x * 4 + wid;
  const float* x = X + (size_t)tok * HDIM;
  float acc[8] = {};
  for (int k0 = 0; k0 < HDIM; k0 += 64) {
    const float xv = x[k0 + lane];
    const float* wrow = Wr + (size_t)(k0 + lane) * NEXP;
    const float4 w0 = *reinterpret_cast<const float4*>(wrow);
    const float4 w1 = *reinterpret_cast<const float4*>(wrow + 4);
    acc[0] = fmaf(xv, w0.x, acc[0]);
    acc[1] = fmaf(xv, w0.y, acc[1]);
    acc[2] = fmaf(xv, w0.z, acc[2]);
    acc[3] = fmaf(xv, w0.w, acc[3]);
    acc[4] = fmaf(xv, w1.x, acc[4]);
    acc[5] = fmaf(xv, w1.y, acc[5]);
    acc[6] = fmaf(xv, w1.z, acc[6]);
    acc[7] = fmaf(xv, w1.w, acc[7]);
  }
#pragma unroll
  for (int e = 0; e < 8; ++e)
#pragma unroll
    for (int o = 32; o > 0; o >>= 1) acc[e] += __shfl_down(acc[e], o);
  if (lane == 0) {
    float mx = -3.0e38f;
#pragma unroll
    for (int e = 0; e < 8; ++e) { acc[e] += br[e]; mx = fmaxf(mx, acc[e]); }
    float sum = 0.f;
#pragma unroll
    for (int e = 0; e < 8; ++e) { acc[e] = expf(acc[e] - mx); sum += acc[e]; }
    const float inv = 1.f / sum;
    int best = 0;
    float bv = acc[0];
#pragma unroll
    for (int e = 0; e < 8; ++e) {
      const float p = acc[e] * inv;
      scores_out[(size_t)tok * NEXP + e] = p;
      if (acc[e] > bv) { bv = acc[e]; best = e; }
    }
    expert[tok] = best;
    atomicAdd(&counts[best], 1);
  }
}

__global__ void offsets_kernel(const int* __restrict__ counts, int* __restrict__ offs)
{
  if (threadIdx.x == 0 && blockIdx.x == 0) {
    int a = 0;
    for (int e = 0; e < NEXP; ++e) { offs[e] = a; a += counts[e]; }
    offs[NEXP] = a;
  }
}

__global__ __launch_bounds__(256) void scatter_kernel(
    const int* __restrict__ expert, const int* __restrict__ offs,
    int* __restrict__ cursor, int* __restrict__ perm)
{
  const int t = blockIdx.x * 256 + threadIdx.x;
  if (t >= TOKS) return;
  const int e = expert[t];
  const int pos = atomicAdd(&cursor[e], 1);
  perm[offs[e] + pos] = t;
}

extern "C" void kernel_launch(void* const* d_in, const int* in_sizes, int n_in,
                              void* d_out, int out_size, void* d_ws, size_t ws_size,
                              hipStream_t stream) {
  const float* hidden = (const float*)d_in[0];
  const float* Wq  = (const float*)d_in[1];
  const float* bq  = (const float*)d_in[2];
  const float* Wk  = (const float*)d_in[3];
  const float* bk  = (const float*)d_in[4];
  const float* Wv  = (const float*)d_in[5];
  const float* bv  = (const float*)d_in[6];
  const float* Wao = (const float*)d_in[7];
  const float* bao = (const float*)d_in[8];
  const float* ln1g = (const float*)d_in[9];
  const float* ln1b = (const float*)d_in[10];
  const float* Wr  = (const float*)d_in[11];
  const float* br  = (const float*)d_in[12];
  const float* Wi  = (const float*)d_in[13];
  const float* bi  = (const float*)d_in[14];
  const float* Wo  = (const float*)d_in[15];
  const float* bo  = (const float*)d_in[16];
  const float* ln2g = (const float*)d_in[17];
  const float* ln2b = (const float*)d_in[18];

  float* out = (float*)d_out;
  float* scores_out = out + (size_t)TOKS * HDIM;

  const size_t M1 = (size_t)TOKS * HDIM;     // 6.29M floats
  const size_t HW = (size_t)HDIM * HDIM;
  float* ws = (float*)d_ws;
  // ---- arena (float offsets, by liveness) ----
  short* QKhb = (short*)ws;                  // [0, M1)   : [8192][1536] bf16 hi (Q|K)
  short* QKlb = (short*)(ws + M1);           // [M1, 2M1)
  short* VThb = (short*)(ws + 2 * M1);       // [2M1, 2.5M1) : [96][64][1024] bf16 hi
  short* VTlb = VThb + (size_t)BATCH * NHEAD * 64 * 1024;   // [2.5M1, 3M1)
  float* ctxb = ws + 3 * M1;                 // [3M1, 4M1)
  float* bqkv = ws + 3 * M1;                 // 2304 f32, dead before attention writes ctxb
  short* Hh = (short*)(ws + 4 * M1);         // hidden split hi  [4M1,4.5M1)
  short* Hl = Hh + M1;                       // hidden split lo  [4.5M1,5M1)
  short* Ch = Hh; short* Cl = Hl;            // ctx split (phase C reuse)
  short* wt = (short*)(ws + 5 * M1);
  short* WqkvhT = wt;                        // [2304][768]
  short* WqkvlT = wt + 3 * HW;
  short* WaohT  = wt + 6 * HW;
  short* WaolT  = wt + 7 * HW;
  float* aoproj   = ws;                      // reuse QKh region (dead after attention)
  float* attn_out = ws + M1;                 // reuse QKl region
  float* tmp2     = ws;
  short* Abf    = (short*)(ws + 2 * M1);     // expert phase (VT dead)
  short* WiT    = Abf + M1;
  short* WoT    = WiT + (size_t)NEXP * FDIM * HDIM;
  short* interb = WoT + (size_t)HDIM * FDIM;
  int* ints   = (int*)(interb + (size_t)TOKS * FDIM);
  int* perm   = ints;
  int* expert = ints + TOKS;
  int* counts = expert + TOKS;
  int* offs   = counts + NEXP;
  int* cursor = offs + NEXP + 1;

  hipMemsetAsync(counts, 0, (NEXP + NEXP + 1 + NEXP) * sizeof(int), stream);
  hipMemcpyAsync(bqkv,        bq, HDIM * sizeof(float), hipMemcpyDeviceToDevice, stream);
  hipMemcpyAsync(bqkv + 768,  bk, HDIM * sizeof(float), hipMemcpyDeviceToDevice, stream);
  hipMemcpyAsync(bqkv + 1536, bv, HDIM * sizeof(float), hipMemcpyDeviceToDevice, stream);

  const dim3 blk(256);
  // --- split prep ---
  convert_split<<<dim3(TOKS * HDIM / 4 / 256), blk, 0, stream>>>(hidden, Hh, Hl, TOKS * HDIM / 4);
  transpose_split<<<dim3(24, 24), blk, 0, stream>>>(Wq,  WqkvhT,          WqkvlT,          HDIM, HDIM);
  transpose_split<<<dim3(24, 24), blk, 0, stream>>>(Wk,  WqkvhT + HW,     WqkvlT + HW,     HDIM, HDIM);
  transpose_split<<<dim3(24, 24), blk, 0, stream>>>(Wv,  WqkvhT + 2 * HW, WqkvlT + 2 * HW, HDIM, HDIM);
  transpose_split<<<dim3(24, 24), blk, 0, stream>>>(Wao, WaohT,           WaolT,           HDIM, HDIM);

  // --- fused QKV projection -> split-bf16 Q,K + transposed split V ---
  qkv_split_mfma<<<dim3(2304 / 128, TOKS / 128), blk, 0, stream>>>(
      Hh, Hl, WqkvhT, WqkvlT, bqkv, QKhb, QKlb, VThb, VTlb);

  // --- MFMA flash attention ---
  attention_mfma<<<dim3(SEQ / 128, NHEAD, BATCH), blk, 0, stream>>>(
      QKhb, QKlb, VThb, VTlb, ctxb);

  // --- AO projection (split-bf16 MFMA) + LN1 ---
  convert_split<<<dim3(TOKS * HDIM / 4 / 256), blk, 0, stream>>>(ctxb, Ch, Cl, TOKS * HDIM / 4);
  gemm_split_mfma<<<dim3(HDIM / 128, TOKS / 128), blk, 0, stream>>>(
      Ch, Cl, WaohT, WaolT, bao, aoproj, HDIM, HDIM);
  add_ln_kernel<<<dim3(TOKS), blk, 0, stream>>>(aoproj, hidden, ln1g, ln1b, attn_out);

  // --- router + dispatch ---
  router_kernel<<<dim3(TOKS / 4), blk, 0, stream>>>(attn_out, Wr, br, scores_out, expert, counts);
  offsets_kernel<<<dim3(1), dim3(64), 0, stream>>>(counts, offs);
  scatter_kernel<<<dim3(TOKS / 256), blk, 0, stream>>>(expert, offs, cursor, perm);

  // --- expert FFN (bf16 MFMA) ---
  transpose_to_bf16<<<dim3(FDIM / 32, HDIM / 32, NEXP), blk, 0, stream>>>(Wi, WiT, HDIM, FDIM);
  transpose_to_bf16<<<dim3(HDIM / 32, FDIM / 32, 1), blk, 0, stream>>>(Wo, WoT, FDIM, HDIM);
  convert_bf16<<<dim3(TOKS * HDIM / 4 / 256), blk, 0, stream>>>(attn_out, Abf, TOKS * HDIM / 4);

  expert_up_mfma<<<dim3(TOKS / 128, FDIM / 128, NEXP), blk, 0, stream>>>(
      Abf, WiT, bi, perm, offs, interb);
  wo_mfma<<<dim3(HDIM / 128, TOKS / 128), blk, 0, stream>>>(interb, WoT, bo, tmp2);
  add_ln_kernel<<<dim3(TOKS), blk, 0, stream>>>(tmp2, attn_out, ln2g, ln2b, out);
}